// Round 9
// baseline (1998.198 us; speedup 1.0000x reference)
//
#include <hip/hip_runtime.h>
#include <hip/hip_bf16.h>
#include <math.h>

#define NN 50000
#define EE 800000
#define MM (EE + NN)   // edges + self loops
#define GG 64
#define SWG 128        // stat partial workgroups

// adaptive int read: handles both int32 and int64 device buffers
__device__ __forceinline__ int geti(const void* p, long idx, int is64) {
    return is64 ? (int)((const long long*)p)[idx] : ((const int*)p)[idx];
}

// int64 little-endian values < 2^31: odd int32 words are all zero.
__global__ void k_detect(const int* __restrict__ ei, int* __restrict__ flag) {
    if (blockIdx.x == 0 && threadIdx.x == 0) {
        int ok = 1;
        for (int k = 0; k < 128; ++k) {
            int lo = ei[2 * k], hi = ei[2 * k + 1];
            if (hi != 0 || (unsigned)lo >= (unsigned)NN) { ok = 0; break; }
        }
        flag[0] = ok;
    }
}

// ---------------- CSR by destination ----------------

__global__ void k_zero(int* p, int n) {
    int i = blockIdx.x * blockDim.x + threadIdx.x;
    if (i < n) p[i] = 0;
}

__global__ void k_count(const void* __restrict__ ei, const int* __restrict__ flag,
                        int* __restrict__ counts) {
    int e = blockIdx.x * blockDim.x + threadIdx.x;
    if (e >= MM) return;
    int is64 = flag[0];
    int d = (e < EE) ? geti(ei, (long)EE + e, is64) : (e - EE);
    if ((unsigned)d < (unsigned)NN) atomicAdd(&counts[d], 1);
}

__global__ void k_scan(const int* __restrict__ counts, int* __restrict__ rowptr) {
    __shared__ int buf[256];
    __shared__ int carry_s;
    int tid = threadIdx.x;
    if (tid == 0) { carry_s = 0; rowptr[0] = 0; }
    __syncthreads();
    for (int base = 0; base < NN; base += 256) {
        int v = (base + tid < NN) ? counts[base + tid] : 0;
        buf[tid] = v;
        __syncthreads();
        for (int off = 1; off < 256; off <<= 1) {
            int t = (tid >= off) ? buf[tid - off] : 0;
            __syncthreads();
            buf[tid] += t;
            __syncthreads();
        }
        int inc = buf[tid] + carry_s;
        if (base + tid < NN) rowptr[base + tid + 1] = inc;
        __syncthreads();
        if (tid == 255) carry_s = inc;
        __syncthreads();
    }
}

__global__ void k_fill(const void* __restrict__ ei, const int* __restrict__ flag,
                       const int* __restrict__ rowptr,
                       int* __restrict__ fill, int* __restrict__ colv) {
    int e = blockIdx.x * blockDim.x + threadIdx.x;
    if (e >= MM) return;
    int is64 = flag[0];
    int s, d;
    if (e < EE) { s = geti(ei, e, is64); d = geti(ei, (long)EE + e, is64); }
    else { s = d = e - EE; }
    if ((unsigned)d >= (unsigned)NN || (unsigned)s >= (unsigned)NN) return;
    int pos = rowptr[d] + atomicAdd(&fill[d], 1);
    if ((unsigned)pos < (unsigned)MM) colv[pos] = s;
}

// ---------------- GEMM: xp[n][c] = sum_k h[n][k] * W[k][c] ----------------

__global__ __launch_bounds__(256) void k_gemm_dumb(const float* __restrict__ h,
                                                   const float* __restrict__ W,
                                                   float* __restrict__ xp, int n) {
    int i = blockIdx.x * 256 + threadIdx.x;   // n*128 + c
    if (i >= n * 128) return;
    int c = i & 127;
    int r = i >> 7;
    const float* hr = h + r * 128;
    float acc = 0.f;
#pragma unroll 8
    for (int k = 0; k < 128; ++k) acc = fmaf(hr[k], W[k * 128 + c], acc);
    xp[i] = acc;
}

// ---------------- attention dots ----------------

__global__ __launch_bounds__(256) void k_attdots(const float* __restrict__ xp,
                                                 const float* __restrict__ attS,
                                                 const float* __restrict__ attD,
                                                 float* __restrict__ als,
                                                 float* __restrict__ ald, int n) {
    int i = blockIdx.x * 256 + threadIdx.x;   // n*8 + h
    if (i >= n * 8) return;
    int hh = i & 7;
    int node = i >> 3;
    const float* xr = xp + node * 128 + hh * 16;
    float ds = 0.f, dd = 0.f;
#pragma unroll
    for (int j = 0; j < 16; ++j) {
        ds = fmaf(xr[j], attS[hh * 16 + j], ds);
        dd = fmaf(xr[j], attD[hh * 16 + j], dd);
    }
    als[i] = ds;
    ald[i] = dd;
}

// ---------------- per-(node,head) softmax max + denom ----------------

__global__ __launch_bounds__(256) void k_maxsum(const float* __restrict__ als,
                                                const float* __restrict__ ald,
                                                const int* __restrict__ rowptr,
                                                const int* __restrict__ colv,
                                                float* __restrict__ Mx,
                                                float* __restrict__ Dn, int n) {
    int i = blockIdx.x * 256 + threadIdx.x;   // n*8 + h
    if (i >= n * 8) return;
    int hh = i & 7;
    int node = i >> 3;
    int rs = rowptr[node], re = rowptr[node + 1];
    float aldn = ald[i];
    float m = -1e30f;
    for (int e = rs; e < re; ++e) {
        int s = colv[e];
        float v = als[s * 8 + hh] + aldn;
        v = v > 0.f ? v : 0.2f * v;
        m = fmaxf(m, v);
    }
    float sum = 0.f;
    for (int e = rs; e < re; ++e) {
        int s = colv[e];
        float v = als[s * 8 + hh] + aldn;
        v = v > 0.f ? v : 0.2f * v;
        sum += expf(v - m);
    }
    Mx[i] = m;
    Dn[i] = sum;
}

// ---------------- gather: y[n][c] = prev + sum_e alpha*xp[src][c] + bias ----------------

__global__ __launch_bounds__(256) void k_gather(const float* __restrict__ xp,
                                                const float* __restrict__ als,
                                                const float* __restrict__ ald,
                                                const float* __restrict__ Mx,
                                                const float* __restrict__ Dn,
                                                const int* __restrict__ rowptr,
                                                const int* __restrict__ colv,
                                                const float* __restrict__ prev,
                                                const float* __restrict__ bias,
                                                float* __restrict__ y, int n) {
    int i = blockIdx.x * 256 + threadIdx.x;   // n*128 + c
    if (i >= n * 128) return;
    int c = i & 127;
    int node = i >> 7;
    int q = c >> 4;
    int rs = rowptr[node], re = rowptr[node + 1];
    float m = Mx[node * 8 + q];
    float invd = 1.f / Dn[node * 8 + q];
    float aldn = ald[node * 8 + q];
    float acc = 0.f;
    for (int e = rs; e < re; ++e) {
        int s = colv[e];
        float v = als[s * 8 + q] + aldn;
        v = v > 0.f ? v : 0.2f * v;
        float a = expf(v - m) * invd;
        acc = fmaf(a, xp[s * 128 + c], acc);
    }
    float p = prev ? prev[i] : 0.f;
    y[i] = p + acc + bias[c];
}

// ---------------- layernorm over axis 0 ----------------

__global__ __launch_bounds__(256) void k_stats(const float* __restrict__ y,
                                               double* __restrict__ partial, int n) {
    int col = threadIdx.x & 127;
    int rg = threadIdx.x >> 7;
    double s = 0.0, s2 = 0.0;
    for (int r = blockIdx.x * 2 + rg; r < n; r += SWG * 2) {
        float v = y[r * 128 + col];
        s += v; s2 += (double)v * (double)v;
    }
    __shared__ double ls[256], ls2[256];
    ls[threadIdx.x] = s; ls2[threadIdx.x] = s2;
    __syncthreads();
    if (rg == 0) {
        s += ls[threadIdx.x + 128];
        s2 += ls2[threadIdx.x + 128];
        partial[col * SWG + blockIdx.x] = s;
        partial[128 * SWG + col * SWG + blockIdx.x] = s2;
    }
}

__global__ void k_stats_fin(const double* __restrict__ partial, float* __restrict__ stats, int n) {
    int col = threadIdx.x;  // 128 threads
    double s = 0.0, s2 = 0.0;
    for (int w = 0; w < SWG; ++w) {
        s += partial[col * SWG + w];
        s2 += partial[128 * SWG + col * SWG + w];
    }
    double mu = s / n;
    double var = s2 / n - mu * mu;
    stats[col] = (float)mu;
    stats[128 + col] = (float)(1.0 / sqrt(var + 1e-5));
}

__global__ __launch_bounds__(256) void k_elem(const float* __restrict__ y,
                                              const float* __restrict__ stats,
                                              const float* __restrict__ gamma,
                                              const float* __restrict__ beta,
                                              float* __restrict__ out, int total)
{
    int i = blockIdx.x * blockDim.x + threadIdx.x;
    if (i >= total) return;
    int col = i & 127;
    float v = (y[i] - stats[col]) * stats[128 + col] * gamma[col] + beta[col];
    out[i] = v > 0.f ? v : expm1f(v);
}

// ---------------- pooling via atomics + readout ----------------

__global__ void k_poolzero(float* acc, int* cnt) {
    int i = blockIdx.x * 256 + threadIdx.x;
    if (i < GG * 128) acc[i] = 0.f;
    if (i < GG) cnt[i] = 0;
}

__global__ __launch_bounds__(256) void k_poolacc(const float* __restrict__ h,
                                                 const void* __restrict__ batch,
                                                 const int* __restrict__ flag,
                                                 float* __restrict__ acc,
                                                 int* __restrict__ cnt, int n) {
    int i = blockIdx.x * 256 + threadIdx.x;   // n*128 + c
    if (i >= n * 128) return;
    int c = i & 127;
    int node = i >> 7;
    int g = geti(batch, node, flag[0]);
    if ((unsigned)g < (unsigned)GG) {
        atomicAdd(&acc[g * 128 + c], h[i]);
        if (c == 0) atomicAdd(&cnt[g], 1);
    }
}

__global__ void k_readout(const float* __restrict__ acc, const int* __restrict__ cnt,
                          const float* __restrict__ row, const float* __restrict__ rob,
                          float* __restrict__ out) {
    int t = threadIdx.x;  // 128 threads
    if (t >= GG * 2) return;
    int g = t >> 1, j = t & 1;
    float inv = 1.f / fmaxf((float)cnt[g], 1.f);
    float s = 0.f;
    for (int c = 0; c < 128; ++c) s = fmaf(acc[g * 128 + c] * inv, row[c * 2 + j], s);
    out[t] = s + rob[j];
}

// ---------------- launch ----------------

extern "C" void kernel_launch(void* const* d_in, const int* in_sizes, int n_in,
                              void* d_out, int out_size, void* d_ws, size_t ws_size,
                              hipStream_t stream) {
    const float* x     = (const float*)d_in[0];
    const void*  ei    = d_in[1];
    const void*  batch = d_in[2];
    const float* W     = (const float*)d_in[3];
    const float* attS  = (const float*)d_in[4];
    const float* attD  = (const float*)d_in[5];
    const float* bias  = (const float*)d_in[6];
    const float* gamma = (const float*)d_in[7];
    const float* beta  = (const float*)d_in[8];
    const float* row   = (const float*)d_in[9];
    const float* rob   = (const float*)d_in[10];
    float* out = (float*)d_out;

    char* wsb = (char*)d_ws;
    size_t off = 0;
    auto alloc = [&](size_t bytes) {
        void* p = wsb + off;
        off += (bytes + 255) & ~(size_t)255;
        return p;
    };
    int*    flag    = (int*)alloc(256);
    int*    rowptr  = (int*)alloc((size_t)(NN + 1) * 4);
    int*    cnts    = (int*)alloc((size_t)NN * 4 * 2);   // counts + fill
    int*    colv    = (int*)alloc((size_t)MM * 4);
    double* partial = (double*)alloc((size_t)128 * SWG * 2 * 8);
    float*  stats   = (float*)alloc(256 * 4);
    float*  ALS     = (float*)alloc((size_t)NN * 8 * 4);
    float*  ALD     = (float*)alloc((size_t)NN * 8 * 4);
    float*  MX      = (float*)alloc((size_t)NN * 8 * 4);
    float*  DN      = (float*)alloc((size_t)NN * 8 * 4);
    float*  pacc    = (float*)alloc((size_t)GG * 128 * 4);
    int*    pcnt    = (int*)alloc((size_t)GG * 4);
    float* XP  = (float*)alloc((size_t)NN * 128 * 4);
    float* Y   = (float*)alloc((size_t)NN * 128 * 4);
    float* HB1 = (float*)alloc((size_t)NN * 128 * 4);
    float* HB2 = (float*)alloc((size_t)NN * 128 * 4);
    (void)ws_size; (void)in_sizes; (void)n_in; (void)out_size;

    int* fill = cnts + NN;
    const int GE = (NN * 128 + 255) / 256;   // element-wise grids
    const int GH = (NN * 8 + 255) / 256;     // (node,head) grids

    hipLaunchKernelGGL(k_detect, dim3(1), dim3(64), 0, stream, (const int*)ei, flag);
    hipLaunchKernelGGL(k_zero, dim3((2 * NN + 255) / 256), dim3(256), 0, stream, cnts, 2 * NN);
    hipLaunchKernelGGL(k_count, dim3((MM + 255) / 256), dim3(256), 0, stream, ei, flag, cnts);
    hipLaunchKernelGGL(k_scan, dim3(1), dim3(256), 0, stream, cnts, rowptr);
    hipLaunchKernelGGL(k_fill, dim3((MM + 255) / 256), dim3(256), 0, stream, ei, flag, rowptr, fill, colv);

    // h chain: inputs {x, HB1, HB2}, outputs {HB1, HB2, XP}
    const float* hs[4] = { x, HB1, HB2, XP };
    for (int b = 0; b < 3; ++b) {
        const float* h = hs[b];
        const float* prev = (b == 0) ? nullptr : hs[b - 1];
        float* hn = (float*)hs[b + 1];

        hipLaunchKernelGGL(k_gemm_dumb, dim3(GE), dim3(256), 0, stream, h, W + b * 16384, XP, NN);
        hipLaunchKernelGGL(k_attdots, dim3(GH), dim3(256), 0, stream,
                           XP, attS + b * 128, attD + b * 128, ALS, ALD, NN);
        hipLaunchKernelGGL(k_maxsum, dim3(GH), dim3(256), 0, stream,
                           ALS, ALD, rowptr, colv, MX, DN, NN);
        hipLaunchKernelGGL(k_gather, dim3(GE), dim3(256), 0, stream,
                           XP, ALS, ALD, MX, DN, rowptr, colv, prev, bias + b * 128, Y, NN);
        hipLaunchKernelGGL(k_stats, dim3(SWG), dim3(256), 0, stream, Y, partial, NN);
        hipLaunchKernelGGL(k_stats_fin, dim3(1), dim3(128), 0, stream, partial, stats, NN);
        hipLaunchKernelGGL(k_elem, dim3(GE), dim3(256), 0, stream,
                           Y, stats, gamma + b * 128, beta + b * 128, hn, NN * 128);  // <-- THE FIX
    }

    hipLaunchKernelGGL(k_poolzero, dim3((GG * 128 + 255) / 256), dim3(256), 0, stream, pacc, pcnt);
    hipLaunchKernelGGL(k_poolacc, dim3(GE), dim3(256), 0, stream, hs[3], batch, flag, pacc, pcnt, NN);
    hipLaunchKernelGGL(k_readout, dim3(1), dim3(128), 0, stream, pacc, pcnt, row, rob, out);
}

// Round 10
// 1321.404 us; speedup vs baseline: 1.5122x; 1.5122x over previous
//
#include <hip/hip_runtime.h>
#include <hip/hip_bf16.h>
#include <math.h>

#define NN 50000
#define EE 800000
#define MM (EE + NN)   // edges + self loops
#define GG 64
#define SWG 128        // stat partial workgroups

// adaptive int read: handles both int32 and int64 device buffers
__device__ __forceinline__ int geti(const void* p, long idx, int is64) {
    return is64 ? (int)((const long long*)p)[idx] : ((const int*)p)[idx];
}

// int64 little-endian values < 2^31: odd int32 words are all zero.
__global__ void k_detect(const int* __restrict__ ei, int* __restrict__ flag) {
    if (blockIdx.x == 0 && threadIdx.x == 0) {
        int ok = 1;
        for (int k = 0; k < 128; ++k) {
            int lo = ei[2 * k], hi = ei[2 * k + 1];
            if (hi != 0 || (unsigned)lo >= (unsigned)NN) { ok = 0; break; }
        }
        flag[0] = ok;
    }
}

// ---------------- CSR by destination ----------------

__global__ void k_zero(int* p, int n) {
    int i = blockIdx.x * blockDim.x + threadIdx.x;
    if (i < n) p[i] = 0;
}

__global__ void k_count(const void* __restrict__ ei, const int* __restrict__ flag,
                        int* __restrict__ counts) {
    int e = blockIdx.x * blockDim.x + threadIdx.x;
    if (e >= MM) return;
    int is64 = flag[0];
    int d = (e < EE) ? geti(ei, (long)EE + e, is64) : (e - EE);
    if ((unsigned)d < (unsigned)NN) atomicAdd(&counts[d], 1);
}

__global__ void k_scan(const int* __restrict__ counts, int* __restrict__ rowptr) {
    __shared__ int buf[256];
    __shared__ int carry_s;
    int tid = threadIdx.x;
    if (tid == 0) { carry_s = 0; rowptr[0] = 0; }
    __syncthreads();
    for (int base = 0; base < NN; base += 256) {
        int v = (base + tid < NN) ? counts[base + tid] : 0;
        buf[tid] = v;
        __syncthreads();
        for (int off = 1; off < 256; off <<= 1) {
            int t = (tid >= off) ? buf[tid - off] : 0;
            __syncthreads();
            buf[tid] += t;
            __syncthreads();
        }
        int inc = buf[tid] + carry_s;
        if (base + tid < NN) rowptr[base + tid + 1] = inc;
        __syncthreads();
        if (tid == 255) carry_s = inc;
        __syncthreads();
    }
}

__global__ void k_fill(const void* __restrict__ ei, const int* __restrict__ flag,
                       const int* __restrict__ rowptr,
                       int* __restrict__ fill, int* __restrict__ colv) {
    int e = blockIdx.x * blockDim.x + threadIdx.x;
    if (e >= MM) return;
    int is64 = flag[0];
    int s, d;
    if (e < EE) { s = geti(ei, e, is64); d = geti(ei, (long)EE + e, is64); }
    else { s = d = e - EE; }
    if ((unsigned)d >= (unsigned)NN || (unsigned)s >= (unsigned)NN) return;
    int pos = rowptr[d] + atomicAdd(&fill[d], 1);
    if ((unsigned)pos < (unsigned)MM) colv[pos] = s;
}

// ---------------- fused tiled GEMM + attention dots ----------------
// xp = h @ W; als/ald fused in epilogue.
// thread = (head=tid&7, r0=tid>>3): 16 cols (one head), rows r0+{0,32,64,96}.

__global__ __launch_bounds__(256) void k_gemm_att(
    const float* __restrict__ h, const float* __restrict__ W,
    const float* __restrict__ attS, const float* __restrict__ attD,
    float* __restrict__ xp, float* __restrict__ als, float* __restrict__ ald, int n)
{
    __shared__ float Wt[32][128];
    __shared__ float Ht[128][33];
    int tid = threadIdx.x;
    int head = tid & 7, r0 = tid >> 3;
    int rbase = blockIdx.x * 128;

    float acc[4][16];
#pragma unroll
    for (int a = 0; a < 4; ++a)
#pragma unroll
        for (int b = 0; b < 16; ++b) acc[a][b] = 0.f;

    for (int k0 = 0; k0 < 128; k0 += 32) {
        // stage W chunk [32 k][128 c]
#pragma unroll
        for (int j = 0; j < 4; ++j) {
            int idx = tid * 16 + j * 4;
            int kk = idx >> 7, c = idx & 127;
            *(float4*)&Wt[kk][c] = *(const float4*)&W[(k0 + kk) * 128 + c];
        }
        // stage H chunk [128 rows][32 k], padded stride 33
#pragma unroll
        for (int j = 0; j < 4; ++j) {
            int f = tid * 16 + j * 4;
            int r = f >> 5, kk = f & 31;
            int gr = rbase + r;
            float4 v = make_float4(0.f, 0.f, 0.f, 0.f);
            if (gr < n) v = *(const float4*)&h[gr * 128 + k0 + kk];
            Ht[r][kk] = v.x; Ht[r][kk + 1] = v.y; Ht[r][kk + 2] = v.z; Ht[r][kk + 3] = v.w;
        }
        __syncthreads();
#pragma unroll
        for (int kk = 0; kk < 32; ++kk) {
            float wv[16];
#pragma unroll
            for (int j = 0; j < 4; ++j)
                *(float4*)&wv[j * 4] = *(const float4*)&Wt[kk][head * 16 + j * 4];
#pragma unroll
            for (int rr = 0; rr < 4; ++rr) {
                float hv = Ht[r0 + rr * 32][kk];
#pragma unroll
                for (int j = 0; j < 16; ++j) acc[rr][j] = fmaf(hv, wv[j], acc[rr][j]);
            }
        }
        __syncthreads();
    }

    float asv[16], adv[16];
#pragma unroll
    for (int j = 0; j < 16; ++j) { asv[j] = attS[head * 16 + j]; adv[j] = attD[head * 16 + j]; }

#pragma unroll
    for (int rr = 0; rr < 4; ++rr) {
        int r = rbase + r0 + rr * 32;
        if (r < n) {
            float ds = 0.f, dd = 0.f;
#pragma unroll
            for (int j = 0; j < 16; ++j) { ds = fmaf(acc[rr][j], asv[j], ds); dd = fmaf(acc[rr][j], adv[j], dd); }
            als[r * 8 + head] = ds;
            ald[r * 8 + head] = dd;
#pragma unroll
            for (int j = 0; j < 4; ++j)
                *(float4*)&xp[r * 128 + head * 16 + j * 4] = *(float4*)&acc[rr][j * 4];
        }
    }
}

// ---------------- per-(node,head) softmax max + denom ----------------

__global__ __launch_bounds__(256) void k_maxsum(const float* __restrict__ als,
                                                const float* __restrict__ ald,
                                                const int* __restrict__ rowptr,
                                                const int* __restrict__ colv,
                                                float* __restrict__ Mx,
                                                float* __restrict__ Dn, int n) {
    int i = blockIdx.x * 256 + threadIdx.x;   // n*8 + h
    if (i >= n * 8) return;
    int hh = i & 7;
    int node = i >> 3;
    int rs = rowptr[node], re = rowptr[node + 1];
    float aldn = ald[i];
    float m = -1e30f;
    for (int e = rs; e < re; ++e) {
        int s = colv[e];
        float v = als[s * 8 + hh] + aldn;
        v = v > 0.f ? v : 0.2f * v;
        m = fmaxf(m, v);
    }
    float sum = 0.f;
    for (int e = rs; e < re; ++e) {
        int s = colv[e];
        float v = als[s * 8 + hh] + aldn;
        v = v > 0.f ? v : 0.2f * v;
        sum += expf(v - m);
    }
    Mx[i] = m;
    Dn[i] = sum;
}

// ---------------- gather: y[n][c] = prev + sum_e alpha*xp[src][c] + bias ----------------

__global__ __launch_bounds__(256) void k_gather(const float* __restrict__ xp,
                                                const float* __restrict__ als,
                                                const float* __restrict__ ald,
                                                const float* __restrict__ Mx,
                                                const float* __restrict__ Dn,
                                                const int* __restrict__ rowptr,
                                                const int* __restrict__ colv,
                                                const float* __restrict__ prev,
                                                const float* __restrict__ bias,
                                                float* __restrict__ y, int n) {
    int i = blockIdx.x * 256 + threadIdx.x;   // n*128 + c
    if (i >= n * 128) return;
    int c = i & 127;
    int node = i >> 7;
    int q = c >> 4;
    int rs = rowptr[node], re = rowptr[node + 1];
    float m = Mx[node * 8 + q];
    float invd = 1.f / Dn[node * 8 + q];
    float aldn = ald[node * 8 + q];
    float acc = 0.f;
    for (int e = rs; e < re; ++e) {
        int s = colv[e];
        float v = als[s * 8 + q] + aldn;
        v = v > 0.f ? v : 0.2f * v;
        float a = expf(v - m) * invd;
        acc = fmaf(a, xp[s * 128 + c], acc);
    }
    float p = prev ? prev[i] : 0.f;
    y[i] = p + acc + bias[c];
}

// ---------------- layernorm over axis 0 ----------------

__global__ __launch_bounds__(256) void k_stats(const float* __restrict__ y,
                                               double* __restrict__ partial, int n) {
    int col = threadIdx.x & 127;
    int rg = threadIdx.x >> 7;
    double s = 0.0, s2 = 0.0;
    for (int r = blockIdx.x * 2 + rg; r < n; r += SWG * 2) {
        float v = y[r * 128 + col];
        s += v; s2 += (double)v * (double)v;
    }
    __shared__ double ls[256], ls2[256];
    ls[threadIdx.x] = s; ls2[threadIdx.x] = s2;
    __syncthreads();
    if (rg == 0) {
        s += ls[threadIdx.x + 128];
        s2 += ls2[threadIdx.x + 128];
        partial[col * SWG + blockIdx.x] = s;
        partial[128 * SWG + col * SWG + blockIdx.x] = s2;
    }
}

__global__ void k_stats_fin(const double* __restrict__ partial, float* __restrict__ stats, int n) {
    int col = threadIdx.x;  // 128 threads
    double s = 0.0, s2 = 0.0;
    for (int w = 0; w < SWG; ++w) {
        s += partial[col * SWG + w];
        s2 += partial[128 * SWG + col * SWG + w];
    }
    double mu = s / n;
    double var = s2 / n - mu * mu;
    stats[col] = (float)mu;
    stats[128 + col] = (float)(1.0 / sqrt(var + 1e-5));
}

__global__ __launch_bounds__(256) void k_elem(const float* __restrict__ y,
                                              const float* __restrict__ stats,
                                              const float* __restrict__ gamma,
                                              const float* __restrict__ beta,
                                              float* __restrict__ out, int total)
{
    int i = blockIdx.x * blockDim.x + threadIdx.x;
    if (i >= total) return;
    int col = i & 127;
    float v = (y[i] - stats[col]) * stats[128 + col] * gamma[col] + beta[col];
    out[i] = v > 0.f ? v : expm1f(v);
}

// ---------------- sorted-range pooling + fused readout (no atomics) ----------------
// batch is sorted ascending (verified); one WG per graph.

__global__ __launch_bounds__(256) void k_pool_sorted(
    const float* __restrict__ h, const void* __restrict__ batch,
    const int* __restrict__ flag, const float* __restrict__ row,
    const float* __restrict__ rob, float* __restrict__ out, int n)
{
    int g = blockIdx.x;
    int is64 = flag[0];
    int lo = 0, hi = n;
    while (lo < hi) { int mid = (lo + hi) >> 1; if (geti(batch, mid, is64) < g) lo = mid + 1; else hi = mid; }
    int start = lo;
    hi = n;
    while (lo < hi) { int mid = (lo + hi) >> 1; if (geti(batch, mid, is64) < g + 1) lo = mid + 1; else hi = mid; }
    int end = lo;
    int cnt = end - start;

    int col = threadIdx.x & 127;
    int half = threadIdx.x >> 7;   // 0 or 1
    float s = 0.f;
    for (int r = start + half; r < end; r += 2) s += h[r * 128 + col];
    __shared__ float ls[256];
    ls[threadIdx.x] = s;
    __syncthreads();
    if (half == 0) {
        float tot = s + ls[col + 128];
        ls[col] = tot * (1.f / fmaxf((float)cnt, 1.f));   // pooled mean
    }
    __syncthreads();
    if (threadIdx.x < 2) {
        float acc = 0.f;
        for (int c = 0; c < 128; ++c) acc = fmaf(ls[c], row[c * 2 + threadIdx.x], acc);
        out[g * 2 + threadIdx.x] = acc + rob[threadIdx.x];
    }
}

// ---------------- launch ----------------

extern "C" void kernel_launch(void* const* d_in, const int* in_sizes, int n_in,
                              void* d_out, int out_size, void* d_ws, size_t ws_size,
                              hipStream_t stream) {
    const float* x     = (const float*)d_in[0];
    const void*  ei    = d_in[1];
    const void*  batch = d_in[2];
    const float* W     = (const float*)d_in[3];
    const float* attS  = (const float*)d_in[4];
    const float* attD  = (const float*)d_in[5];
    const float* bias  = (const float*)d_in[6];
    const float* gamma = (const float*)d_in[7];
    const float* beta  = (const float*)d_in[8];
    const float* row   = (const float*)d_in[9];
    const float* rob   = (const float*)d_in[10];
    float* out = (float*)d_out;

    char* wsb = (char*)d_ws;
    size_t off = 0;
    auto alloc = [&](size_t bytes) {
        void* p = wsb + off;
        off += (bytes + 255) & ~(size_t)255;
        return p;
    };
    int*    flag    = (int*)alloc(256);
    int*    rowptr  = (int*)alloc((size_t)(NN + 1) * 4);
    int*    cnts    = (int*)alloc((size_t)NN * 4 * 2);   // counts + fill
    int*    colv    = (int*)alloc((size_t)MM * 4);
    double* partial = (double*)alloc((size_t)128 * SWG * 2 * 8);
    float*  stats   = (float*)alloc(256 * 4);
    float*  ALS     = (float*)alloc((size_t)NN * 8 * 4);
    float*  ALD     = (float*)alloc((size_t)NN * 8 * 4);
    float*  MX      = (float*)alloc((size_t)NN * 8 * 4);
    float*  DN      = (float*)alloc((size_t)NN * 8 * 4);
    float* XP  = (float*)alloc((size_t)NN * 128 * 4);
    float* Y   = (float*)alloc((size_t)NN * 128 * 4);
    float* HB1 = (float*)alloc((size_t)NN * 128 * 4);
    float* HB2 = (float*)alloc((size_t)NN * 128 * 4);
    (void)ws_size; (void)in_sizes; (void)n_in; (void)out_size;

    int* fill = cnts + NN;
    const int GE = (NN * 128 + 255) / 256;   // element-wise grids
    const int GH = (NN * 8 + 255) / 256;     // (node,head) grids

    hipLaunchKernelGGL(k_detect, dim3(1), dim3(64), 0, stream, (const int*)ei, flag);
    hipLaunchKernelGGL(k_zero, dim3((2 * NN + 255) / 256), dim3(256), 0, stream, cnts, 2 * NN);
    hipLaunchKernelGGL(k_count, dim3((MM + 255) / 256), dim3(256), 0, stream, ei, flag, cnts);
    hipLaunchKernelGGL(k_scan, dim3(1), dim3(256), 0, stream, cnts, rowptr);
    hipLaunchKernelGGL(k_fill, dim3((MM + 255) / 256), dim3(256), 0, stream, ei, flag, rowptr, fill, colv);

    // h chain: inputs {x, HB1, HB2}, outputs {HB1, HB2, XP}
    const float* hs[4] = { x, HB1, HB2, XP };
    for (int b = 0; b < 3; ++b) {
        const float* h = hs[b];
        const float* prev = (b == 0) ? nullptr : hs[b - 1];
        float* hn = (float*)hs[b + 1];

        hipLaunchKernelGGL(k_gemm_att, dim3((NN + 127) / 128), dim3(256), 0, stream,
                           h, W + b * 16384, attS + b * 128, attD + b * 128, XP, ALS, ALD, NN);
        hipLaunchKernelGGL(k_maxsum, dim3(GH), dim3(256), 0, stream,
                           ALS, ALD, rowptr, colv, MX, DN, NN);
        hipLaunchKernelGGL(k_gather, dim3(GE), dim3(256), 0, stream,
                           XP, ALS, ALD, MX, DN, rowptr, colv, prev, bias + b * 128, Y, NN);
        hipLaunchKernelGGL(k_stats, dim3(SWG), dim3(256), 0, stream, Y, partial, NN);
        hipLaunchKernelGGL(k_stats_fin, dim3(1), dim3(128), 0, stream, partial, stats, NN);
        hipLaunchKernelGGL(k_elem, dim3(GE), dim3(256), 0, stream,
                           Y, stats, gamma + b * 128, beta + b * 128, hn, NN * 128);
    }

    hipLaunchKernelGGL(k_pool_sorted, dim3(GG), dim3(256), 0, stream,
                       hs[3], batch, flag, row, rob, out, NN);
}

// Round 11
// 961.203 us; speedup vs baseline: 2.0789x; 1.3747x over previous
//
#include <hip/hip_runtime.h>
#include <hip/hip_bf16.h>
#include <math.h>

#define NN 50000
#define EE 800000
#define MM (EE + NN)   // edges + self loops
#define GG 64
#define SWG 512        // stat partial workgroups
#define NSB ((NN + 255) / 256)   // scan blocks = 196

// adaptive int read: handles both int32 and int64 device buffers
__device__ __forceinline__ int geti(const void* p, long idx, int is64) {
    return is64 ? (int)((const long long*)p)[idx] : ((const int*)p)[idx];
}

// int64 little-endian values < 2^31: odd int32 words are all zero.
__global__ void k_detect(const int* __restrict__ ei, int* __restrict__ flag) {
    if (blockIdx.x == 0 && threadIdx.x == 0) {
        int ok = 1;
        for (int k = 0; k < 128; ++k) {
            int lo = ei[2 * k], hi = ei[2 * k + 1];
            if (hi != 0 || (unsigned)lo >= (unsigned)NN) { ok = 0; break; }
        }
        flag[0] = ok;
    }
}

// ---------------- CSR by destination ----------------

__global__ void k_zero(int* p, int n) {
    int i = blockIdx.x * blockDim.x + threadIdx.x;
    if (i < n) p[i] = 0;
}

__global__ void k_count(const void* __restrict__ ei, const int* __restrict__ flag,
                        int* __restrict__ counts) {
    int e = blockIdx.x * blockDim.x + threadIdx.x;
    if (e >= MM) return;
    int is64 = flag[0];
    int d = (e < EE) ? geti(ei, (long)EE + e, is64) : (e - EE);
    if ((unsigned)d < (unsigned)NN) atomicAdd(&counts[d], 1);
}

// parallel scan: per-block inclusive scan + block sums
__global__ __launch_bounds__(256) void k_scan1(const int* __restrict__ counts,
                                               int* __restrict__ rowptr,
                                               int* __restrict__ bsum) {
    __shared__ int buf[256];
    int b = blockIdx.x, tid = threadIdx.x;
    int i = b * 256 + tid;
    int v = (i < NN) ? counts[i] : 0;
    buf[tid] = v;
    __syncthreads();
    for (int off = 1; off < 256; off <<= 1) {
        int t = (tid >= off) ? buf[tid - off] : 0;
        __syncthreads();
        buf[tid] += t;
        __syncthreads();
    }
    if (i < NN) rowptr[i + 1] = buf[tid];
    if (tid == 255) bsum[b] = buf[255];
}

// scan of block sums (NSB=196 <= 256), in place -> exclusive offsets
__global__ __launch_bounds__(256) void k_scan2(int* __restrict__ bsum) {
    __shared__ int buf[256];
    int tid = threadIdx.x;
    int v = (tid < NSB) ? bsum[tid] : 0;
    buf[tid] = v;
    __syncthreads();
    for (int off = 1; off < 256; off <<= 1) {
        int t = (tid >= off) ? buf[tid - off] : 0;
        __syncthreads();
        buf[tid] += t;
        __syncthreads();
    }
    if (tid < NSB) bsum[tid] = (tid == 0) ? 0 : buf[tid - 1];
}

__global__ __launch_bounds__(256) void k_scan3(int* __restrict__ rowptr,
                                               const int* __restrict__ bsum) {
    int b = blockIdx.x, tid = threadIdx.x;
    int i = b * 256 + tid;
    if (i < NN) rowptr[i + 1] += bsum[b];
    if (b == 0 && tid == 0) rowptr[0] = 0;
}

__global__ void k_fill(const void* __restrict__ ei, const int* __restrict__ flag,
                       const int* __restrict__ rowptr,
                       int* __restrict__ fill, int* __restrict__ colv) {
    int e = blockIdx.x * blockDim.x + threadIdx.x;
    if (e >= MM) return;
    int is64 = flag[0];
    int s, d;
    if (e < EE) { s = geti(ei, e, is64); d = geti(ei, (long)EE + e, is64); }
    else { s = d = e - EE; }
    if ((unsigned)d >= (unsigned)NN || (unsigned)s >= (unsigned)NN) return;
    int pos = rowptr[d] + atomicAdd(&fill[d], 1);
    if ((unsigned)pos < (unsigned)MM) colv[pos] = s;
}

// ---------------- fused tiled GEMM + attention dots ----------------

__global__ __launch_bounds__(256) void k_gemm_att(
    const float* __restrict__ h, const float* __restrict__ W,
    const float* __restrict__ attS, const float* __restrict__ attD,
    float* __restrict__ xp, float* __restrict__ als, float* __restrict__ ald, int n)
{
    __shared__ float Wt[32][128];
    __shared__ float Ht[128][33];
    int tid = threadIdx.x;
    int head = tid & 7, r0 = tid >> 3;
    int rbase = blockIdx.x * 128;

    float acc[4][16];
#pragma unroll
    for (int a = 0; a < 4; ++a)
#pragma unroll
        for (int b = 0; b < 16; ++b) acc[a][b] = 0.f;

    for (int k0 = 0; k0 < 128; k0 += 32) {
#pragma unroll
        for (int j = 0; j < 4; ++j) {
            int idx = tid * 16 + j * 4;
            int kk = idx >> 7, c = idx & 127;
            *(float4*)&Wt[kk][c] = *(const float4*)&W[(k0 + kk) * 128 + c];
        }
#pragma unroll
        for (int j = 0; j < 4; ++j) {
            int f = tid * 16 + j * 4;
            int r = f >> 5, kk = f & 31;
            int gr = rbase + r;
            float4 v = make_float4(0.f, 0.f, 0.f, 0.f);
            if (gr < n) v = *(const float4*)&h[gr * 128 + k0 + kk];
            Ht[r][kk] = v.x; Ht[r][kk + 1] = v.y; Ht[r][kk + 2] = v.z; Ht[r][kk + 3] = v.w;
        }
        __syncthreads();
#pragma unroll
        for (int kk = 0; kk < 32; ++kk) {
            float wv[16];
#pragma unroll
            for (int j = 0; j < 4; ++j)
                *(float4*)&wv[j * 4] = *(const float4*)&Wt[kk][head * 16 + j * 4];
#pragma unroll
            for (int rr = 0; rr < 4; ++rr) {
                float hv = Ht[r0 + rr * 32][kk];
#pragma unroll
                for (int j = 0; j < 16; ++j) acc[rr][j] = fmaf(hv, wv[j], acc[rr][j]);
            }
        }
        __syncthreads();
    }

    float asv[16], adv[16];
#pragma unroll
    for (int j = 0; j < 16; ++j) { asv[j] = attS[head * 16 + j]; adv[j] = attD[head * 16 + j]; }

#pragma unroll
    for (int rr = 0; rr < 4; ++rr) {
        int r = rbase + r0 + rr * 32;
        if (r < n) {
            float ds = 0.f, dd = 0.f;
#pragma unroll
            for (int j = 0; j < 16; ++j) { ds = fmaf(acc[rr][j], asv[j], ds); dd = fmaf(acc[rr][j], adv[j], dd); }
            als[r * 8 + head] = ds;
            ald[r * 8 + head] = dd;
#pragma unroll
            for (int j = 0; j < 4; ++j)
                *(float4*)&xp[r * 128 + head * 16 + j * 4] = *(float4*)&acc[rr][j * 4];
        }
    }
}

// ---------------- fused wave-per-node softmax + gather ----------------
// phases 1+2: lane=(edge_slot ee=lane>>3, head hd=lane&7), shfl_xor reduce.
// phase 3: lanes 0..7 compute the 8 alphas per edge, shfl-broadcast;
//          each lane accumulates channel pair c0=2*lane of head q=lane>>3.

__global__ __launch_bounds__(256) void k_agg(
    const float* __restrict__ xp, const float* __restrict__ als,
    const float* __restrict__ ald,
    const int* __restrict__ rowptr, const int* __restrict__ colv,
    const float* __restrict__ prev, const float* __restrict__ bias,
    float* __restrict__ y, int n)
{
    int wid = (int)((blockIdx.x * blockDim.x + threadIdx.x) >> 6);
    int lane = threadIdx.x & 63;
    if (wid >= n) return;
    int rs = rowptr[wid], re = rowptr[wid + 1];
    int deg = re - rs;

    int hd = lane & 7;
    int ee = lane >> 3;
    float aldn = ald[wid * 8 + hd];

    float m = -1e30f;
    for (int b = ee; b < deg; b += 8) {
        int s = colv[rs + b];
        float v = als[s * 8 + hd] + aldn;
        v = v > 0.f ? v : 0.2f * v;
        m = fmaxf(m, v);
    }
    m = fmaxf(m, __shfl_xor(m, 8));
    m = fmaxf(m, __shfl_xor(m, 16));
    m = fmaxf(m, __shfl_xor(m, 32));

    float sm = 0.f;
    for (int b = ee; b < deg; b += 8) {
        int s = colv[rs + b];
        float v = als[s * 8 + hd] + aldn;
        v = v > 0.f ? v : 0.2f * v;
        sm += expf(v - m);
    }
    sm += __shfl_xor(sm, 8);
    sm += __shfl_xor(sm, 16);
    sm += __shfl_xor(sm, 32);

    // lanes 0..7 now hold m, 1/sm, aldn for heads 0..7 (hd == lane there)
    float inv = 1.f / sm;
    int q = lane >> 3;
    int c0 = lane * 2;

    float a0 = 0.f, a1 = 0.f;
    for (int e = rs; e < re; ++e) {
        int s = colv[e];
        float a8 = 0.f;
        if (lane < 8) {
            float v = als[s * 8 + lane] + aldn;
            v = v > 0.f ? v : 0.2f * v;
            a8 = expf(v - m) * inv;
        }
        float a = __shfl(a8, q);
        float2 xv = *(const float2*)(xp + s * 128 + c0);
        a0 = fmaf(a, xv.x, a0);
        a1 = fmaf(a, xv.y, a1);
    }
    float p0 = prev ? prev[wid * 128 + c0] : 0.f;
    float p1 = prev ? prev[wid * 128 + c0 + 1] : 0.f;
    y[wid * 128 + c0] = p0 + a0 + bias[c0];
    y[wid * 128 + c0 + 1] = p1 + a1 + bias[c0 + 1];
}

// ---------------- layernorm over axis 0 ----------------

__global__ __launch_bounds__(256) void k_stats(const float* __restrict__ y,
                                               double* __restrict__ partial, int n) {
    int col = threadIdx.x & 127;
    int rg = threadIdx.x >> 7;
    double s = 0.0, s2 = 0.0;
    for (int r = blockIdx.x * 2 + rg; r < n; r += SWG * 2) {
        float v = y[r * 128 + col];
        s += v; s2 += (double)v * (double)v;
    }
    __shared__ double ls[256], ls2[256];
    ls[threadIdx.x] = s; ls2[threadIdx.x] = s2;
    __syncthreads();
    if (rg == 0) {
        s += ls[threadIdx.x + 128];
        s2 += ls2[threadIdx.x + 128];
        partial[col * SWG + blockIdx.x] = s;
        partial[128 * SWG + col * SWG + blockIdx.x] = s2;
    }
}

__global__ void k_stats_fin(const double* __restrict__ partial, float* __restrict__ stats, int n) {
    int col = threadIdx.x;  // 128 threads
    double s = 0.0, s2 = 0.0;
    for (int w = 0; w < SWG; ++w) {
        s += partial[col * SWG + w];
        s2 += partial[128 * SWG + col * SWG + w];
    }
    double mu = s / n;
    double var = s2 / n - mu * mu;
    stats[col] = (float)mu;
    stats[128 + col] = (float)(1.0 / sqrt(var + 1e-5));
}

__global__ __launch_bounds__(256) void k_elem(const float* __restrict__ y,
                                              const float* __restrict__ stats,
                                              const float* __restrict__ gamma,
                                              const float* __restrict__ beta,
                                              float* __restrict__ out, int total)
{
    int i = blockIdx.x * blockDim.x + threadIdx.x;
    if (i >= total) return;
    int col = i & 127;
    float v = (y[i] - stats[col]) * stats[128 + col] * gamma[col] + beta[col];
    out[i] = v > 0.f ? v : expm1f(v);
}

// ---------------- sorted-range pooling + fused readout (no atomics) ----------------

__global__ __launch_bounds__(256) void k_pool_sorted(
    const float* __restrict__ h, const void* __restrict__ batch,
    const int* __restrict__ flag, const float* __restrict__ row,
    const float* __restrict__ rob, float* __restrict__ out, int n)
{
    int g = blockIdx.x;
    int is64 = flag[0];
    int lo = 0, hi = n;
    while (lo < hi) { int mid = (lo + hi) >> 1; if (geti(batch, mid, is64) < g) lo = mid + 1; else hi = mid; }
    int start = lo;
    hi = n;
    while (lo < hi) { int mid = (lo + hi) >> 1; if (geti(batch, mid, is64) < g + 1) lo = mid + 1; else hi = mid; }
    int end = lo;
    int cnt = end - start;

    int col = threadIdx.x & 127;
    int half = threadIdx.x >> 7;
    float s = 0.f;
    for (int r = start + half; r < end; r += 2) s += h[r * 128 + col];
    __shared__ float ls[256];
    ls[threadIdx.x] = s;
    __syncthreads();
    if (half == 0) {
        float tot = s + ls[col + 128];
        ls[col] = tot * (1.f / fmaxf((float)cnt, 1.f));
    }
    __syncthreads();
    if (threadIdx.x < 2) {
        float acc = 0.f;
        for (int c = 0; c < 128; ++c) acc = fmaf(ls[c], row[c * 2 + threadIdx.x], acc);
        out[g * 2 + threadIdx.x] = acc + rob[threadIdx.x];
    }
}

// ---------------- launch ----------------

extern "C" void kernel_launch(void* const* d_in, const int* in_sizes, int n_in,
                              void* d_out, int out_size, void* d_ws, size_t ws_size,
                              hipStream_t stream) {
    const float* x     = (const float*)d_in[0];
    const void*  ei    = d_in[1];
    const void*  batch = d_in[2];
    const float* W     = (const float*)d_in[3];
    const float* attS  = (const float*)d_in[4];
    const float* attD  = (const float*)d_in[5];
    const float* bias  = (const float*)d_in[6];
    const float* gamma = (const float*)d_in[7];
    const float* beta  = (const float*)d_in[8];
    const float* row   = (const float*)d_in[9];
    const float* rob   = (const float*)d_in[10];
    float* out = (float*)d_out;

    char* wsb = (char*)d_ws;
    size_t off = 0;
    auto alloc = [&](size_t bytes) {
        void* p = wsb + off;
        off += (bytes + 255) & ~(size_t)255;
        return p;
    };
    int*    flag    = (int*)alloc(256);
    int*    rowptr  = (int*)alloc((size_t)(NN + 1) * 4);
    int*    cnts    = (int*)alloc((size_t)NN * 4 * 2);   // counts + fill
    int*    bsum    = (int*)alloc((size_t)256 * 4);
    int*    colv    = (int*)alloc((size_t)MM * 4);
    double* partial = (double*)alloc((size_t)128 * SWG * 2 * 8);
    float*  stats   = (float*)alloc(256 * 4);
    float*  ALS     = (float*)alloc((size_t)NN * 8 * 4);
    float*  ALD     = (float*)alloc((size_t)NN * 8 * 4);
    float* XP  = (float*)alloc((size_t)NN * 128 * 4);
    float* Y   = (float*)alloc((size_t)NN * 128 * 4);
    float* HB1 = (float*)alloc((size_t)NN * 128 * 4);
    float* HB2 = (float*)alloc((size_t)NN * 128 * 4);
    (void)ws_size; (void)in_sizes; (void)n_in; (void)out_size;

    int* fill = cnts + NN;
    const int GE = (NN * 128 + 255) / 256;

    hipLaunchKernelGGL(k_detect, dim3(1), dim3(64), 0, stream, (const int*)ei, flag);
    hipLaunchKernelGGL(k_zero, dim3((2 * NN + 255) / 256), dim3(256), 0, stream, cnts, 2 * NN);
    hipLaunchKernelGGL(k_count, dim3((MM + 255) / 256), dim3(256), 0, stream, ei, flag, cnts);
    hipLaunchKernelGGL(k_scan1, dim3(NSB), dim3(256), 0, stream, cnts, rowptr, bsum);
    hipLaunchKernelGGL(k_scan2, dim3(1), dim3(256), 0, stream, bsum);
    hipLaunchKernelGGL(k_scan3, dim3(NSB), dim3(256), 0, stream, rowptr, bsum);
    hipLaunchKernelGGL(k_fill, dim3((MM + 255) / 256), dim3(256), 0, stream, ei, flag, rowptr, fill, colv);

    // h chain: inputs {x, HB1, HB2}, outputs {HB1, HB2, XP}
    const float* hs[4] = { x, HB1, HB2, XP };
    for (int b = 0; b < 3; ++b) {
        const float* h = hs[b];
        const float* prev = (b == 0) ? nullptr : hs[b - 1];
        float* hn = (float*)hs[b + 1];

        hipLaunchKernelGGL(k_gemm_att, dim3((NN + 127) / 128), dim3(256), 0, stream,
                           h, W + b * 16384, attS + b * 128, attD + b * 128, XP, ALS, ALD, NN);
        hipLaunchKernelGGL(k_agg, dim3((NN + 3) / 4), dim3(256), 0, stream,
                           XP, ALS, ALD, rowptr, colv, prev, bias + b * 128, Y, NN);
        hipLaunchKernelGGL(k_stats, dim3(SWG), dim3(256), 0, stream, Y, partial, NN);
        hipLaunchKernelGGL(k_stats_fin, dim3(1), dim3(128), 0, stream, partial, stats, NN);
        hipLaunchKernelGGL(k_elem, dim3(GE), dim3(256), 0, stream,
                           Y, stats, gamma + b * 128, beta + b * 128, hn, NN * 128);
    }

    hipLaunchKernelGGL(k_pool_sorted, dim3(GG), dim3(256), 0, stream,
                       hs[3], batch, flag, row, rob, out, NN);
}

// Round 12
// 747.684 us; speedup vs baseline: 2.6725x; 1.2856x over previous
//
#include <hip/hip_runtime.h>
#include <hip/hip_bf16.h>
#include <math.h>

#define NN 50000
#define EE 800000
#define MM (EE + NN)   // edges + self loops
#define GG 64
#define SWG 512        // stat partial workgroups
#define NSB ((NN + 255) / 256)   // scan blocks = 196

// adaptive int read: handles both int32 and int64 device buffers
__device__ __forceinline__ int geti(const void* p, long idx, int is64) {
    return is64 ? (int)((const long long*)p)[idx] : ((const int*)p)[idx];
}

// int64 little-endian values < 2^31: odd int32 words are all zero.
__global__ void k_detect(const int* __restrict__ ei, int* __restrict__ flag) {
    if (blockIdx.x == 0 && threadIdx.x == 0) {
        int ok = 1;
        for (int k = 0; k < 128; ++k) {
            int lo = ei[2 * k], hi = ei[2 * k + 1];
            if (hi != 0 || (unsigned)lo >= (unsigned)NN) { ok = 0; break; }
        }
        flag[0] = ok;
    }
}

// ---------------- CSR by destination ----------------

__global__ void k_zero(int* p, int n) {
    int i = blockIdx.x * blockDim.x + threadIdx.x;
    if (i < n) p[i] = 0;
}

__global__ void k_count(const void* __restrict__ ei, const int* __restrict__ flag,
                        int* __restrict__ counts) {
    int e = blockIdx.x * blockDim.x + threadIdx.x;
    if (e >= MM) return;
    int is64 = flag[0];
    int d = (e < EE) ? geti(ei, (long)EE + e, is64) : (e - EE);
    if ((unsigned)d < (unsigned)NN) atomicAdd(&counts[d], 1);
}

// parallel scan: per-block inclusive scan + block sums
__global__ __launch_bounds__(256) void k_scan1(const int* __restrict__ counts,
                                               int* __restrict__ rowptr,
                                               int* __restrict__ bsum) {
    __shared__ int buf[256];
    int b = blockIdx.x, tid = threadIdx.x;
    int i = b * 256 + tid;
    int v = (i < NN) ? counts[i] : 0;
    buf[tid] = v;
    __syncthreads();
    for (int off = 1; off < 256; off <<= 1) {
        int t = (tid >= off) ? buf[tid - off] : 0;
        __syncthreads();
        buf[tid] += t;
        __syncthreads();
    }
    if (i < NN) rowptr[i + 1] = buf[tid];
    if (tid == 255) bsum[b] = buf[255];
}

// scan of block sums (NSB=196 <= 256), in place -> exclusive offsets
__global__ __launch_bounds__(256) void k_scan2(int* __restrict__ bsum) {
    __shared__ int buf[256];
    int tid = threadIdx.x;
    int v = (tid < NSB) ? bsum[tid] : 0;
    buf[tid] = v;
    __syncthreads();
    for (int off = 1; off < 256; off <<= 1) {
        int t = (tid >= off) ? buf[tid - off] : 0;
        __syncthreads();
        buf[tid] += t;
        __syncthreads();
    }
    if (tid < NSB) bsum[tid] = (tid == 0) ? 0 : buf[tid - 1];
}

__global__ __launch_bounds__(256) void k_scan3(int* __restrict__ rowptr,
                                               const int* __restrict__ bsum) {
    int b = blockIdx.x, tid = threadIdx.x;
    int i = b * 256 + tid;
    if (i < NN) rowptr[i + 1] += bsum[b];
    if (b == 0 && tid == 0) rowptr[0] = 0;
}

__global__ void k_fill(const void* __restrict__ ei, const int* __restrict__ flag,
                       const int* __restrict__ rowptr,
                       int* __restrict__ fill, int* __restrict__ colv) {
    int e = blockIdx.x * blockDim.x + threadIdx.x;
    if (e >= MM) return;
    int is64 = flag[0];
    int s, d;
    if (e < EE) { s = geti(ei, e, is64); d = geti(ei, (long)EE + e, is64); }
    else { s = d = e - EE; }
    if ((unsigned)d >= (unsigned)NN || (unsigned)s >= (unsigned)NN) return;
    int pos = rowptr[d] + atomicAdd(&fill[d], 1);
    if ((unsigned)pos < (unsigned)MM) colv[pos] = s;
}

// ---------------- fused tiled GEMM + attention dots ----------------

__global__ __launch_bounds__(256) void k_gemm_att(
    const float* __restrict__ h, const float* __restrict__ W,
    const float* __restrict__ attS, const float* __restrict__ attD,
    float* __restrict__ xp, float* __restrict__ als, float* __restrict__ ald, int n)
{
    __shared__ float Wt[32][128];
    __shared__ float Ht[128][33];
    int tid = threadIdx.x;
    int head = tid & 7, r0 = tid >> 3;
    int rbase = blockIdx.x * 128;

    float acc[4][16];
#pragma unroll
    for (int a = 0; a < 4; ++a)
#pragma unroll
        for (int b = 0; b < 16; ++b) acc[a][b] = 0.f;

    for (int k0 = 0; k0 < 128; k0 += 32) {
#pragma unroll
        for (int j = 0; j < 4; ++j) {
            int idx = tid * 16 + j * 4;
            int kk = idx >> 7, c = idx & 127;
            *(float4*)&Wt[kk][c] = *(const float4*)&W[(k0 + kk) * 128 + c];
        }
#pragma unroll
        for (int j = 0; j < 4; ++j) {
            int f = tid * 16 + j * 4;
            int r = f >> 5, kk = f & 31;
            int gr = rbase + r;
            float4 v = make_float4(0.f, 0.f, 0.f, 0.f);
            if (gr < n) v = *(const float4*)&h[gr * 128 + k0 + kk];
            Ht[r][kk] = v.x; Ht[r][kk + 1] = v.y; Ht[r][kk + 2] = v.z; Ht[r][kk + 3] = v.w;
        }
        __syncthreads();
#pragma unroll
        for (int kk = 0; kk < 32; ++kk) {
            float wv[16];
#pragma unroll
            for (int j = 0; j < 4; ++j)
                *(float4*)&wv[j * 4] = *(const float4*)&Wt[kk][head * 16 + j * 4];
#pragma unroll
            for (int rr = 0; rr < 4; ++rr) {
                float hv = Ht[r0 + rr * 32][kk];
#pragma unroll
                for (int j = 0; j < 16; ++j) acc[rr][j] = fmaf(hv, wv[j], acc[rr][j]);
            }
        }
        __syncthreads();
    }

    float asv[16], adv[16];
#pragma unroll
    for (int j = 0; j < 16; ++j) { asv[j] = attS[head * 16 + j]; adv[j] = attD[head * 16 + j]; }

#pragma unroll
    for (int rr = 0; rr < 4; ++rr) {
        int r = rbase + r0 + rr * 32;
        if (r < n) {
            float ds = 0.f, dd = 0.f;
#pragma unroll
            for (int j = 0; j < 16; ++j) { ds = fmaf(acc[rr][j], asv[j], ds); dd = fmaf(acc[rr][j], adv[j], dd); }
            als[r * 8 + head] = ds;
            ald[r * 8 + head] = dd;
#pragma unroll
            for (int j = 0; j < 4; ++j)
                *(float4*)&xp[r * 128 + head * 16 + j * 4] = *(float4*)&acc[rr][j * 4];
        }
    }
}

// ---------------- fused wave-per-node softmax + gather (LDS-batched alphas) ----------------
// phases 1+2: lane=(ee=lane>>3, hd=lane&7), butterfly reduce -> every lane holds
//             its head's max m and denom sm.
// phase 3: per batch of 8 edges, all 64 lanes compute alpha[ee][hd] in parallel
//          (no shfl, no divergence), stash in LDS, then an unrolled 8-step gather
//          issues 8 independent 512B xp loads.

__global__ __launch_bounds__(256) void k_agg(
    const float* __restrict__ xp, const float* __restrict__ als,
    const float* __restrict__ ald,
    const int* __restrict__ rowptr, const int* __restrict__ colv,
    const float* __restrict__ prev, const float* __restrict__ bias,
    float* __restrict__ y, int n)
{
    __shared__ float alds[4][8][8];   // [wave][edge][head]
    __shared__ int   slds[4][8];      // [wave][edge]
    int wv = threadIdx.x >> 6;
    int wid = (int)((blockIdx.x * blockDim.x + threadIdx.x) >> 6);
    int lane = threadIdx.x & 63;
    if (wid >= n) return;
    int rs = rowptr[wid], re = rowptr[wid + 1];
    int deg = re - rs;

    int hd = lane & 7;
    int ee = lane >> 3;
    float aldn = ald[wid * 8 + hd];

    float m = -1e30f;
    for (int b = ee; b < deg; b += 8) {
        int s = colv[rs + b];
        float v = als[s * 8 + hd] + aldn;
        v = v > 0.f ? v : 0.2f * v;
        m = fmaxf(m, v);
    }
    m = fmaxf(m, __shfl_xor(m, 8));
    m = fmaxf(m, __shfl_xor(m, 16));
    m = fmaxf(m, __shfl_xor(m, 32));

    float sm = 0.f;
    for (int b = ee; b < deg; b += 8) {
        int s = colv[rs + b];
        float v = als[s * 8 + hd] + aldn;
        v = v > 0.f ? v : 0.2f * v;
        sm += expf(v - m);
    }
    sm += __shfl_xor(sm, 8);
    sm += __shfl_xor(sm, 16);
    sm += __shfl_xor(sm, 32);

    float inv = 1.f / sm;
    int q = lane >> 3;
    int c0 = lane * 2;

    float a0 = 0.f, a1 = 0.f;
    int full = deg & ~7;

    for (int b0 = 0; b0 < full; b0 += 8) {
        // all 64 lanes compute one alpha each (edge b0+ee, head hd)
        int se = colv[rs + b0 + ee];
        float v = als[se * 8 + hd] + aldn;
        v = v > 0.f ? v : 0.2f * v;
        float al = expf(v - m) * inv;
        alds[wv][ee][hd] = al;
        if (hd == 0) slds[wv][ee] = se;
        // wave-synchronous: compiler orders ds_read after ds_write via lgkmcnt
#pragma unroll
        for (int j = 0; j < 8; ++j) {
            int s = slds[wv][j];
            float a = alds[wv][j][q];
            float2 xv = *(const float2*)(xp + s * 128 + c0);
            a0 = fmaf(a, xv.x, a0);
            a1 = fmaf(a, xv.y, a1);
        }
    }

    // tail (deg & 7 edges)
    if (full < deg) {
        int nb = deg - full;
        float al = 0.f;
        int se = 0;
        if (ee < nb) {
            se = colv[rs + full + ee];
            float v = als[se * 8 + hd] + aldn;
            v = v > 0.f ? v : 0.2f * v;
            al = expf(v - m) * inv;
        }
        alds[wv][ee][hd] = al;
        if (hd == 0) slds[wv][ee] = se;
        for (int j = 0; j < nb; ++j) {
            int s = slds[wv][j];
            float a = alds[wv][j][q];
            float2 xv = *(const float2*)(xp + s * 128 + c0);
            a0 = fmaf(a, xv.x, a0);
            a1 = fmaf(a, xv.y, a1);
        }
    }

    float p0 = prev ? prev[wid * 128 + c0] : 0.f;
    float p1 = prev ? prev[wid * 128 + c0 + 1] : 0.f;
    y[wid * 128 + c0] = p0 + a0 + bias[c0];
    y[wid * 128 + c0 + 1] = p1 + a1 + bias[c0 + 1];
}

// ---------------- layernorm over axis 0 ----------------

__global__ __launch_bounds__(256) void k_stats(const float* __restrict__ y,
                                               double* __restrict__ partial, int n) {
    int col = threadIdx.x & 127;
    int rg = threadIdx.x >> 7;
    double s = 0.0, s2 = 0.0;
    for (int r = blockIdx.x * 2 + rg; r < n; r += SWG * 2) {
        float v = y[r * 128 + col];
        s += v; s2 += (double)v * (double)v;
    }
    __shared__ double ls[256], ls2[256];
    ls[threadIdx.x] = s; ls2[threadIdx.x] = s2;
    __syncthreads();
    if (rg == 0) {
        s += ls[threadIdx.x + 128];
        s2 += ls2[threadIdx.x + 128];
        partial[col * SWG + blockIdx.x] = s;
        partial[128 * SWG + col * SWG + blockIdx.x] = s2;
    }
}

__global__ void k_stats_fin(const double* __restrict__ partial, float* __restrict__ stats, int n) {
    int col = threadIdx.x;  // 128 threads
    double s = 0.0, s2 = 0.0;
    for (int w = 0; w < SWG; ++w) {
        s += partial[col * SWG + w];
        s2 += partial[128 * SWG + col * SWG + w];
    }
    double mu = s / n;
    double var = s2 / n - mu * mu;
    stats[col] = (float)mu;
    stats[128 + col] = (float)(1.0 / sqrt(var + 1e-5));
}

__global__ __launch_bounds__(256) void k_elem(const float* __restrict__ y,
                                              const float* __restrict__ stats,
                                              const float* __restrict__ gamma,
                                              const float* __restrict__ beta,
                                              float* __restrict__ out, int total)
{
    int i = blockIdx.x * blockDim.x + threadIdx.x;
    if (i >= total) return;
    int col = i & 127;
    float v = (y[i] - stats[col]) * stats[128 + col] * gamma[col] + beta[col];
    out[i] = v > 0.f ? v : expm1f(v);
}

// ---------------- sorted-range pooling + fused readout (no atomics) ----------------

__global__ __launch_bounds__(256) void k_pool_sorted(
    const float* __restrict__ h, const void* __restrict__ batch,
    const int* __restrict__ flag, const float* __restrict__ row,
    const float* __restrict__ rob, float* __restrict__ out, int n)
{
    int g = blockIdx.x;
    int is64 = flag[0];
    int lo = 0, hi = n;
    while (lo < hi) { int mid = (lo + hi) >> 1; if (geti(batch, mid, is64) < g) lo = mid + 1; else hi = mid; }
    int start = lo;
    hi = n;
    while (lo < hi) { int mid = (lo + hi) >> 1; if (geti(batch, mid, is64) < g + 1) lo = mid + 1; else hi = mid; }
    int end = lo;
    int cnt = end - start;

    int col = threadIdx.x & 127;
    int half = threadIdx.x >> 7;
    float s = 0.f;
    for (int r = start + half; r < end; r += 2) s += h[r * 128 + col];
    __shared__ float ls[256];
    ls[threadIdx.x] = s;
    __syncthreads();
    if (half == 0) {
        float tot = s + ls[col + 128];
        ls[col] = tot * (1.f / fmaxf((float)cnt, 1.f));
    }
    __syncthreads();
    if (threadIdx.x < 2) {
        float acc = 0.f;
        for (int c = 0; c < 128; ++c) acc = fmaf(ls[c], row[c * 2 + threadIdx.x], acc);
        out[g * 2 + threadIdx.x] = acc + rob[threadIdx.x];
    }
}

// ---------------- launch ----------------

extern "C" void kernel_launch(void* const* d_in, const int* in_sizes, int n_in,
                              void* d_out, int out_size, void* d_ws, size_t ws_size,
                              hipStream_t stream) {
    const float* x     = (const float*)d_in[0];
    const void*  ei    = d_in[1];
    const void*  batch = d_in[2];
    const float* W     = (const float*)d_in[3];
    const float* attS  = (const float*)d_in[4];
    const float* attD  = (const float*)d_in[5];
    const float* bias  = (const float*)d_in[6];
    const float* gamma = (const float*)d_in[7];
    const float* beta  = (const float*)d_in[8];
    const float* row   = (const float*)d_in[9];
    const float* rob   = (const float*)d_in[10];
    float* out = (float*)d_out;

    char* wsb = (char*)d_ws;
    size_t off = 0;
    auto alloc = [&](size_t bytes) {
        void* p = wsb + off;
        off += (bytes + 255) & ~(size_t)255;
        return p;
    };
    int*    flag    = (int*)alloc(256);
    int*    rowptr  = (int*)alloc((size_t)(NN + 1) * 4);
    int*    cnts    = (int*)alloc((size_t)NN * 4 * 2);   // counts + fill
    int*    bsum    = (int*)alloc((size_t)256 * 4);
    int*    colv    = (int*)alloc((size_t)MM * 4);
    double* partial = (double*)alloc((size_t)128 * SWG * 2 * 8);
    float*  stats   = (float*)alloc(256 * 4);
    float*  ALS     = (float*)alloc((size_t)NN * 8 * 4);
    float*  ALD     = (float*)alloc((size_t)NN * 8 * 4);
    float* XP  = (float*)alloc((size_t)NN * 128 * 4);
    float* Y   = (float*)alloc((size_t)NN * 128 * 4);
    float* HB1 = (float*)alloc((size_t)NN * 128 * 4);
    float* HB2 = (float*)alloc((size_t)NN * 128 * 4);
    (void)ws_size; (void)in_sizes; (void)n_in; (void)out_size;

    int* fill = cnts + NN;
    const int GE = (NN * 128 + 255) / 256;

    hipLaunchKernelGGL(k_detect, dim3(1), dim3(64), 0, stream, (const int*)ei, flag);
    hipLaunchKernelGGL(k_zero, dim3((2 * NN + 255) / 256), dim3(256), 0, stream, cnts, 2 * NN);
    hipLaunchKernelGGL(k_count, dim3((MM + 255) / 256), dim3(256), 0, stream, ei, flag, cnts);
    hipLaunchKernelGGL(k_scan1, dim3(NSB), dim3(256), 0, stream, cnts, rowptr, bsum);
    hipLaunchKernelGGL(k_scan2, dim3(1), dim3(256), 0, stream, bsum);
    hipLaunchKernelGGL(k_scan3, dim3(NSB), dim3(256), 0, stream, rowptr, bsum);
    hipLaunchKernelGGL(k_fill, dim3((MM + 255) / 256), dim3(256), 0, stream, ei, flag, rowptr, fill, colv);

    // h chain: inputs {x, HB1, HB2}, outputs {HB1, HB2, XP}
    const float* hs[4] = { x, HB1, HB2, XP };
    for (int b = 0; b < 3; ++b) {
        const float* h = hs[b];
        const float* prev = (b == 0) ? nullptr : hs[b - 1];
        float* hn = (float*)hs[b + 1];

        hipLaunchKernelGGL(k_gemm_att, dim3((NN + 127) / 128), dim3(256), 0, stream,
                           h, W + b * 16384, attS + b * 128, attD + b * 128, XP, ALS, ALD, NN);
        hipLaunchKernelGGL(k_agg, dim3((NN + 3) / 4), dim3(256), 0, stream,
                           XP, ALS, ALD, rowptr, colv, prev, bias + b * 128, Y, NN);
        hipLaunchKernelGGL(k_stats, dim3(SWG), dim3(256), 0, stream, Y, partial, NN);
        hipLaunchKernelGGL(k_stats_fin, dim3(1), dim3(128), 0, stream, partial, stats, NN);
        hipLaunchKernelGGL(k_elem, dim3(GE), dim3(256), 0, stream,
                           Y, stats, gamma + b * 128, beta + b * 128, hn, NN * 128);
    }

    hipLaunchKernelGGL(k_pool_sorted, dim3(GG), dim3(256), 0, stream,
                       hs[3], batch, flag, row, rob, out, NN);
}

// Round 13
// 661.516 us; speedup vs baseline: 3.0206x; 1.1303x over previous
//
#include <hip/hip_runtime.h>
#include <hip/hip_bf16.h>
#include <math.h>

#define NN 50000
#define EE 800000
#define MM (EE + NN)   // edges + self loops
#define GG 64
#define SWG 512        // stat partial workgroups
#define NSB ((NN + 255) / 256)   // scan blocks = 196
#define PSP 16         // pooling splits per group

// adaptive int read: handles both int32 and int64 device buffers
__device__ __forceinline__ int geti(const void* p, long idx, int is64) {
    return is64 ? (int)((const long long*)p)[idx] : ((const int*)p)[idx];
}

// int64 little-endian values < 2^31: odd int32 words are all zero.
__global__ void k_detect(const int* __restrict__ ei, int* __restrict__ flag) {
    if (blockIdx.x == 0 && threadIdx.x == 0) {
        int ok = 1;
        for (int k = 0; k < 128; ++k) {
            int lo = ei[2 * k], hi = ei[2 * k + 1];
            if (hi != 0 || (unsigned)lo >= (unsigned)NN) { ok = 0; break; }
        }
        flag[0] = ok;
    }
}

// ---------------- CSR by destination ----------------

__global__ void k_zero(int* p, int n) {
    int i = blockIdx.x * blockDim.x + threadIdx.x;
    if (i < n) p[i] = 0;
}

__global__ void k_count(const void* __restrict__ ei, const int* __restrict__ flag,
                        int* __restrict__ counts) {
    int e = blockIdx.x * blockDim.x + threadIdx.x;
    if (e >= MM) return;
    int is64 = flag[0];
    int d = (e < EE) ? geti(ei, (long)EE + e, is64) : (e - EE);
    if ((unsigned)d < (unsigned)NN) atomicAdd(&counts[d], 1);
}

// parallel scan: per-block inclusive scan + block sums
__global__ __launch_bounds__(256) void k_scan1(const int* __restrict__ counts,
                                               int* __restrict__ rowptr,
                                               int* __restrict__ bsum) {
    __shared__ int buf[256];
    int b = blockIdx.x, tid = threadIdx.x;
    int i = b * 256 + tid;
    int v = (i < NN) ? counts[i] : 0;
    buf[tid] = v;
    __syncthreads();
    for (int off = 1; off < 256; off <<= 1) {
        int t = (tid >= off) ? buf[tid - off] : 0;
        __syncthreads();
        buf[tid] += t;
        __syncthreads();
    }
    if (i < NN) rowptr[i + 1] = buf[tid];
    if (tid == 255) bsum[b] = buf[255];
}

// scan of block sums (NSB=196 <= 256), in place -> exclusive offsets
__global__ __launch_bounds__(256) void k_scan2(int* __restrict__ bsum) {
    __shared__ int buf[256];
    int tid = threadIdx.x;
    int v = (tid < NSB) ? bsum[tid] : 0;
    buf[tid] = v;
    __syncthreads();
    for (int off = 1; off < 256; off <<= 1) {
        int t = (tid >= off) ? buf[tid - off] : 0;
        __syncthreads();
        buf[tid] += t;
        __syncthreads();
    }
    if (tid < NSB) bsum[tid] = (tid == 0) ? 0 : buf[tid - 1];
}

__global__ __launch_bounds__(256) void k_scan3(int* __restrict__ rowptr,
                                               const int* __restrict__ bsum) {
    int b = blockIdx.x, tid = threadIdx.x;
    int i = b * 256 + tid;
    if (i < NN) rowptr[i + 1] += bsum[b];
    if (b == 0 && tid == 0) rowptr[0] = 0;
}

__global__ void k_fill(const void* __restrict__ ei, const int* __restrict__ flag,
                       const int* __restrict__ rowptr,
                       int* __restrict__ fill, int* __restrict__ colv) {
    int e = blockIdx.x * blockDim.x + threadIdx.x;
    if (e >= MM) return;
    int is64 = flag[0];
    int s, d;
    if (e < EE) { s = geti(ei, e, is64); d = geti(ei, (long)EE + e, is64); }
    else { s = d = e - EE; }
    if ((unsigned)d >= (unsigned)NN || (unsigned)s >= (unsigned)NN) return;
    int pos = rowptr[d] + atomicAdd(&fill[d], 1);
    if ((unsigned)pos < (unsigned)MM) colv[pos] = s;
}

// ---------------- fused tiled GEMM + attention dots ----------------

__global__ __launch_bounds__(256) void k_gemm_att(
    const float* __restrict__ h, const float* __restrict__ W,
    const float* __restrict__ attS, const float* __restrict__ attD,
    float* __restrict__ xp, float* __restrict__ als, float* __restrict__ ald, int n)
{
    __shared__ float Wt[32][128];
    __shared__ float Ht[128][33];
    int tid = threadIdx.x;
    int head = tid & 7, r0 = tid >> 3;
    int rbase = blockIdx.x * 128;

    float acc[4][16];
#pragma unroll
    for (int a = 0; a < 4; ++a)
#pragma unroll
        for (int b = 0; b < 16; ++b) acc[a][b] = 0.f;

    for (int k0 = 0; k0 < 128; k0 += 32) {
#pragma unroll
        for (int j = 0; j < 4; ++j) {
            int idx = tid * 16 + j * 4;
            int kk = idx >> 7, c = idx & 127;
            *(float4*)&Wt[kk][c] = *(const float4*)&W[(k0 + kk) * 128 + c];
        }
#pragma unroll
        for (int j = 0; j < 4; ++j) {
            int f = tid * 16 + j * 4;
            int r = f >> 5, kk = f & 31;
            int gr = rbase + r;
            float4 v = make_float4(0.f, 0.f, 0.f, 0.f);
            if (gr < n) v = *(const float4*)&h[gr * 128 + k0 + kk];
            Ht[r][kk] = v.x; Ht[r][kk + 1] = v.y; Ht[r][kk + 2] = v.z; Ht[r][kk + 3] = v.w;
        }
        __syncthreads();
#pragma unroll
        for (int kk = 0; kk < 32; ++kk) {
            float wv[16];
#pragma unroll
            for (int j = 0; j < 4; ++j)
                *(float4*)&wv[j * 4] = *(const float4*)&Wt[kk][head * 16 + j * 4];
#pragma unroll
            for (int rr = 0; rr < 4; ++rr) {
                float hv = Ht[r0 + rr * 32][kk];
#pragma unroll
                for (int j = 0; j < 16; ++j) acc[rr][j] = fmaf(hv, wv[j], acc[rr][j]);
            }
        }
        __syncthreads();
    }

    float asv[16], adv[16];
#pragma unroll
    for (int j = 0; j < 16; ++j) { asv[j] = attS[head * 16 + j]; adv[j] = attD[head * 16 + j]; }

#pragma unroll
    for (int rr = 0; rr < 4; ++rr) {
        int r = rbase + r0 + rr * 32;
        if (r < n) {
            float ds = 0.f, dd = 0.f;
#pragma unroll
            for (int j = 0; j < 16; ++j) { ds = fmaf(acc[rr][j], asv[j], ds); dd = fmaf(acc[rr][j], adv[j], dd); }
            als[r * 8 + head] = ds;
            ald[r * 8 + head] = dd;
#pragma unroll
            for (int j = 0; j < 4; ++j)
                *(float4*)&xp[r * 128 + head * 16 + j * 4] = *(float4*)&acc[rr][j * 4];
        }
    }
}

// ---------------- fused wave-per-node softmax + gather (LDS-batched alphas) ----------------

__global__ __launch_bounds__(256) void k_agg(
    const float* __restrict__ xp, const float* __restrict__ als,
    const float* __restrict__ ald,
    const int* __restrict__ rowptr, const int* __restrict__ colv,
    const float* __restrict__ prev, const float* __restrict__ bias,
    float* __restrict__ y, int n)
{
    __shared__ float alds[4][8][8];   // [wave][edge][head]
    __shared__ int   slds[4][8];      // [wave][edge]
    int wv = threadIdx.x >> 6;
    int wid = (int)((blockIdx.x * blockDim.x + threadIdx.x) >> 6);
    int lane = threadIdx.x & 63;
    if (wid >= n) return;
    int rs = rowptr[wid], re = rowptr[wid + 1];
    int deg = re - rs;

    int hd = lane & 7;
    int ee = lane >> 3;
    float aldn = ald[wid * 8 + hd];

    float m = -1e30f;
    for (int b = ee; b < deg; b += 8) {
        int s = colv[rs + b];
        float v = als[s * 8 + hd] + aldn;
        v = v > 0.f ? v : 0.2f * v;
        m = fmaxf(m, v);
    }
    m = fmaxf(m, __shfl_xor(m, 8));
    m = fmaxf(m, __shfl_xor(m, 16));
    m = fmaxf(m, __shfl_xor(m, 32));

    float sm = 0.f;
    for (int b = ee; b < deg; b += 8) {
        int s = colv[rs + b];
        float v = als[s * 8 + hd] + aldn;
        v = v > 0.f ? v : 0.2f * v;
        sm += expf(v - m);
    }
    sm += __shfl_xor(sm, 8);
    sm += __shfl_xor(sm, 16);
    sm += __shfl_xor(sm, 32);

    float inv = 1.f / sm;
    int q = lane >> 3;
    int c0 = lane * 2;

    float a0 = 0.f, a1 = 0.f;
    int full = deg & ~7;

    for (int b0 = 0; b0 < full; b0 += 8) {
        int se = colv[rs + b0 + ee];
        float v = als[se * 8 + hd] + aldn;
        v = v > 0.f ? v : 0.2f * v;
        float al = expf(v - m) * inv;
        alds[wv][ee][hd] = al;
        if (hd == 0) slds[wv][ee] = se;
#pragma unroll
        for (int j = 0; j < 8; ++j) {
            int s = slds[wv][j];
            float a = alds[wv][j][q];
            float2 xv = *(const float2*)(xp + s * 128 + c0);
            a0 = fmaf(a, xv.x, a0);
            a1 = fmaf(a, xv.y, a1);
        }
    }

    if (full < deg) {
        int nb = deg - full;
        float al = 0.f;
        int se = 0;
        if (ee < nb) {
            se = colv[rs + full + ee];
            float v = als[se * 8 + hd] + aldn;
            v = v > 0.f ? v : 0.2f * v;
            al = expf(v - m) * inv;
        }
        alds[wv][ee][hd] = al;
        if (hd == 0) slds[wv][ee] = se;
        for (int j = 0; j < nb; ++j) {
            int s = slds[wv][j];
            float a = alds[wv][j][q];
            float2 xv = *(const float2*)(xp + s * 128 + c0);
            a0 = fmaf(a, xv.x, a0);
            a1 = fmaf(a, xv.y, a1);
        }
    }

    float p0 = prev ? prev[wid * 128 + c0] : 0.f;
    float p1 = prev ? prev[wid * 128 + c0 + 1] : 0.f;
    y[wid * 128 + c0] = p0 + a0 + bias[c0];
    y[wid * 128 + c0 + 1] = p1 + a1 + bias[c0 + 1];
}

// ---------------- layernorm over axis 0 ----------------

__global__ __launch_bounds__(256) void k_stats(const float* __restrict__ y,
                                               double* __restrict__ partial, int n) {
    int col = threadIdx.x & 127;
    int rg = threadIdx.x >> 7;
    double s = 0.0, s2 = 0.0;
    for (int r = blockIdx.x * 2 + rg; r < n; r += SWG * 2) {
        float v = y[r * 128 + col];
        s += v; s2 += (double)v * (double)v;
    }
    __shared__ double ls[256], ls2[256];
    ls[threadIdx.x] = s; ls2[threadIdx.x] = s2;
    __syncthreads();
    if (rg == 0) {
        s += ls[threadIdx.x + 128];
        s2 += ls2[threadIdx.x + 128];
        partial[col * SWG + blockIdx.x] = s;
        partial[128 * SWG + col * SWG + blockIdx.x] = s2;
    }
}

__global__ void k_stats_fin(const double* __restrict__ partial, float* __restrict__ stats, int n) {
    int col = threadIdx.x;  // 128 threads
    double s = 0.0, s2 = 0.0;
    for (int w = 0; w < SWG; ++w) {
        s += partial[col * SWG + w];
        s2 += partial[128 * SWG + col * SWG + w];
    }
    double mu = s / n;
    double var = s2 / n - mu * mu;
    stats[col] = (float)mu;
    stats[128 + col] = (float)(1.0 / sqrt(var + 1e-5));
}

__global__ __launch_bounds__(256) void k_elem(const float* __restrict__ y,
                                              const float* __restrict__ stats,
                                              const float* __restrict__ gamma,
                                              const float* __restrict__ beta,
                                              float* __restrict__ out, int total)
{
    int i = blockIdx.x * blockDim.x + threadIdx.x;
    if (i >= total) return;
    int col = i & 127;
    float v = (y[i] - stats[col]) * stats[128 + col] * gamma[col] + beta[col];
    out[i] = v > 0.f ? v : expm1f(v);
}

// ---------------- pooling: split stage + reduce/readout ----------------
// stage 1: grid GG*PSP blocks; block (g, sp) sums its slice of group g's rows.

__global__ __launch_bounds__(256) void k_pool_part(
    const float* __restrict__ h, const void* __restrict__ batch,
    const int* __restrict__ flag, float* __restrict__ ppart, int n)
{
    int g = blockIdx.x / PSP;
    int sp = blockIdx.x % PSP;
    int is64 = flag[0];
    int lo = 0, hi = n;
    while (lo < hi) { int mid = (lo + hi) >> 1; if (geti(batch, mid, is64) < g) lo = mid + 1; else hi = mid; }
    int start = lo;
    hi = n;
    while (lo < hi) { int mid = (lo + hi) >> 1; if (geti(batch, mid, is64) < g + 1) lo = mid + 1; else hi = mid; }
    int end = lo;
    int cnt = end - start;
    int slice = (cnt + PSP - 1) / PSP;
    int s0 = start + sp * slice;
    int s1 = s0 + slice; if (s1 > end) s1 = end;

    int col = threadIdx.x & 127;
    int half = threadIdx.x >> 7;
    float s = 0.f;
    for (int r = s0 + half; r < s1; r += 2) s += h[r * 128 + col];
    __shared__ float ls[256];
    ls[threadIdx.x] = s;
    __syncthreads();
    if (half == 0) ppart[(g * PSP + sp) * 128 + col] = s + ls[col + 128];
}

// stage 2: one block per group; reduce PSP partials, mean, project.
__global__ __launch_bounds__(128) void k_pool_fin(
    const float* __restrict__ ppart, const void* __restrict__ batch,
    const int* __restrict__ flag, const float* __restrict__ row,
    const float* __restrict__ rob, float* __restrict__ out, int n)
{
    int g = blockIdx.x;
    int is64 = flag[0];
    int lo = 0, hi = n;
    while (lo < hi) { int mid = (lo + hi) >> 1; if (geti(batch, mid, is64) < g) lo = mid + 1; else hi = mid; }
    int start = lo;
    hi = n;
    while (lo < hi) { int mid = (lo + hi) >> 1; if (geti(batch, mid, is64) < g + 1) lo = mid + 1; else hi = mid; }
    int cnt = lo - start;

    int col = threadIdx.x;   // 128
    float s = 0.f;
#pragma unroll
    for (int sp = 0; sp < PSP; ++sp) s += ppart[(g * PSP + sp) * 128 + col];
    __shared__ float ls[128];
    ls[col] = s * (1.f / fmaxf((float)cnt, 1.f));
    __syncthreads();
    if (col < 2) {
        float acc = 0.f;
        for (int c = 0; c < 128; ++c) acc = fmaf(ls[c], row[c * 2 + col], acc);
        out[g * 2 + col] = acc + rob[col];
    }
}

// ---------------- launch ----------------

extern "C" void kernel_launch(void* const* d_in, const int* in_sizes, int n_in,
                              void* d_out, int out_size, void* d_ws, size_t ws_size,
                              hipStream_t stream) {
    const float* x     = (const float*)d_in[0];
    const void*  ei    = d_in[1];
    const void*  batch = d_in[2];
    const float* W     = (const float*)d_in[3];
    const float* attS  = (const float*)d_in[4];
    const float* attD  = (const float*)d_in[5];
    const float* bias  = (const float*)d_in[6];
    const float* gamma = (const float*)d_in[7];
    const float* beta  = (const float*)d_in[8];
    const float* row   = (const float*)d_in[9];
    const float* rob   = (const float*)d_in[10];
    float* out = (float*)d_out;

    char* wsb = (char*)d_ws;
    size_t off = 0;
    auto alloc = [&](size_t bytes) {
        void* p = wsb + off;
        off += (bytes + 255) & ~(size_t)255;
        return p;
    };
    int*    flag    = (int*)alloc(256);
    int*    rowptr  = (int*)alloc((size_t)(NN + 1) * 4);
    int*    cnts    = (int*)alloc((size_t)NN * 4 * 2);   // counts + fill
    int*    bsum    = (int*)alloc((size_t)256 * 4);
    int*    colv    = (int*)alloc((size_t)MM * 4);
    double* partial = (double*)alloc((size_t)128 * SWG * 2 * 8);
    float*  stats   = (float*)alloc(256 * 4);
    float*  ppart   = (float*)alloc((size_t)GG * PSP * 128 * 4);
    float*  ALS     = (float*)alloc((size_t)NN * 8 * 4);
    float*  ALD     = (float*)alloc((size_t)NN * 8 * 4);
    float* XP  = (float*)alloc((size_t)NN * 128 * 4);
    float* Y   = (float*)alloc((size_t)NN * 128 * 4);
    float* HB1 = (float*)alloc((size_t)NN * 128 * 4);
    float* HB2 = (float*)alloc((size_t)NN * 128 * 4);
    (void)ws_size; (void)in_sizes; (void)n_in; (void)out_size;

    int* fill = cnts + NN;
    const int GE = (NN * 128 + 255) / 256;

    hipLaunchKernelGGL(k_detect, dim3(1), dim3(64), 0, stream, (const int*)ei, flag);
    hipLaunchKernelGGL(k_zero, dim3((2 * NN + 255) / 256), dim3(256), 0, stream, cnts, 2 * NN);
    hipLaunchKernelGGL(k_count, dim3((MM + 255) / 256), dim3(256), 0, stream, ei, flag, cnts);
    hipLaunchKernelGGL(k_scan1, dim3(NSB), dim3(256), 0, stream, cnts, rowptr, bsum);
    hipLaunchKernelGGL(k_scan2, dim3(1), dim3(256), 0, stream, bsum);
    hipLaunchKernelGGL(k_scan3, dim3(NSB), dim3(256), 0, stream, rowptr, bsum);
    hipLaunchKernelGGL(k_fill, dim3((MM + 255) / 256), dim3(256), 0, stream, ei, flag, rowptr, fill, colv);

    // h chain: inputs {x, HB1, HB2}, outputs {HB1, HB2, XP}
    const float* hs[4] = { x, HB1, HB2, XP };
    for (int b = 0; b < 3; ++b) {
        const float* h = hs[b];
        const float* prev = (b == 0) ? nullptr : hs[b - 1];
        float* hn = (float*)hs[b + 1];

        hipLaunchKernelGGL(k_gemm_att, dim3((NN + 127) / 128), dim3(256), 0, stream,
                           h, W + b * 16384, attS + b * 128, attD + b * 128, XP, ALS, ALD, NN);
        hipLaunchKernelGGL(k_agg, dim3((NN + 3) / 4), dim3(256), 0, stream,
                           XP, ALS, ALD, rowptr, colv, prev, bias + b * 128, Y, NN);
        hipLaunchKernelGGL(k_stats, dim3(SWG), dim3(256), 0, stream, Y, partial, NN);
        hipLaunchKernelGGL(k_stats_fin, dim3(1), dim3(128), 0, stream, partial, stats, NN);
        hipLaunchKernelGGL(k_elem, dim3(GE), dim3(256), 0, stream,
                           Y, stats, gamma + b * 128, beta + b * 128, hn, NN * 128);
    }

    hipLaunchKernelGGL(k_pool_part, dim3(GG * PSP), dim3(256), 0, stream,
                       hs[3], batch, flag, ppart, NN);
    hipLaunchKernelGGL(k_pool_fin, dim3(GG), dim3(128), 0, stream,
                       ppart, batch, flag, row, rob, out, NN);
}

// Round 14
// 581.555 us; speedup vs baseline: 3.4360x; 1.1375x over previous
//
#include <hip/hip_runtime.h>
#include <hip/hip_bf16.h>
#include <math.h>

#define NN 50000
#define EE 800000
#define MM (EE + NN)   // edges + self loops
#define GG 64
#define SWG 512        // stat partial workgroups
#define NSB ((NN + 255) / 256)   // scan blocks = 196
#define PSP 16         // pooling splits per group

// adaptive int read: handles both int32 and int64 device buffers
__device__ __forceinline__ int geti(const void* p, long idx, int is64) {
    return is64 ? (int)((const long long*)p)[idx] : ((const int*)p)[idx];
}

__device__ __forceinline__ float bf2f(unsigned short u) {
    return __uint_as_float(((unsigned)u) << 16);
}

// int64 little-endian values < 2^31: odd int32 words are all zero.
__global__ void k_detect(const int* __restrict__ ei, int* __restrict__ flag) {
    if (blockIdx.x == 0 && threadIdx.x == 0) {
        int ok = 1;
        for (int k = 0; k < 128; ++k) {
            int lo = ei[2 * k], hi = ei[2 * k + 1];
            if (hi != 0 || (unsigned)lo >= (unsigned)NN) { ok = 0; break; }
        }
        flag[0] = ok;
    }
}

// ---------------- CSR by destination ----------------

__global__ void k_zero(int* p, int n) {
    int i = blockIdx.x * blockDim.x + threadIdx.x;
    if (i < n) p[i] = 0;
}

__global__ void k_count(const void* __restrict__ ei, const int* __restrict__ flag,
                        int* __restrict__ counts) {
    int e = blockIdx.x * blockDim.x + threadIdx.x;
    if (e >= MM) return;
    int is64 = flag[0];
    int d = (e < EE) ? geti(ei, (long)EE + e, is64) : (e - EE);
    if ((unsigned)d < (unsigned)NN) atomicAdd(&counts[d], 1);
}

// parallel scan: per-block inclusive scan + block sums
__global__ __launch_bounds__(256) void k_scan1(const int* __restrict__ counts,
                                               int* __restrict__ rowptr,
                                               int* __restrict__ bsum) {
    __shared__ int buf[256];
    int b = blockIdx.x, tid = threadIdx.x;
    int i = b * 256 + tid;
    int v = (i < NN) ? counts[i] : 0;
    buf[tid] = v;
    __syncthreads();
    for (int off = 1; off < 256; off <<= 1) {
        int t = (tid >= off) ? buf[tid - off] : 0;
        __syncthreads();
        buf[tid] += t;
        __syncthreads();
    }
    if (i < NN) rowptr[i + 1] = buf[tid];
    if (tid == 255) bsum[b] = buf[255];
}

__global__ __launch_bounds__(256) void k_scan2(int* __restrict__ bsum) {
    __shared__ int buf[256];
    int tid = threadIdx.x;
    int v = (tid < NSB) ? bsum[tid] : 0;
    buf[tid] = v;
    __syncthreads();
    for (int off = 1; off < 256; off <<= 1) {
        int t = (tid >= off) ? buf[tid - off] : 0;
        __syncthreads();
        buf[tid] += t;
        __syncthreads();
    }
    if (tid < NSB) bsum[tid] = (tid == 0) ? 0 : buf[tid - 1];
}

__global__ __launch_bounds__(256) void k_scan3(int* __restrict__ rowptr,
                                               const int* __restrict__ bsum) {
    int b = blockIdx.x, tid = threadIdx.x;
    int i = b * 256 + tid;
    if (i < NN) rowptr[i + 1] += bsum[b];
    if (b == 0 && tid == 0) rowptr[0] = 0;
}

__global__ void k_fill(const void* __restrict__ ei, const int* __restrict__ flag,
                       const int* __restrict__ rowptr,
                       int* __restrict__ fill, int* __restrict__ colv) {
    int e = blockIdx.x * blockDim.x + threadIdx.x;
    if (e >= MM) return;
    int is64 = flag[0];
    int s, d;
    if (e < EE) { s = geti(ei, e, is64); d = geti(ei, (long)EE + e, is64); }
    else { s = d = e - EE; }
    if ((unsigned)d >= (unsigned)NN || (unsigned)s >= (unsigned)NN) return;
    int pos = rowptr[d] + atomicAdd(&fill[d], 1);
    if ((unsigned)pos < (unsigned)MM) colv[pos] = s;
}

// ---------------- fused tiled GEMM + attention dots (bf16 xp out) ----------------

__global__ __launch_bounds__(256) void k_gemm_att(
    const float* __restrict__ h, const float* __restrict__ W,
    const float* __restrict__ attS, const float* __restrict__ attD,
    unsigned short* __restrict__ xpb, float* __restrict__ als,
    float* __restrict__ ald, int n)
{
    __shared__ float Wt[32][128];
    __shared__ float Ht[128][33];
    int tid = threadIdx.x;
    int head = tid & 7, r0 = tid >> 3;
    int rbase = blockIdx.x * 128;

    float acc[4][16];
#pragma unroll
    for (int a = 0; a < 4; ++a)
#pragma unroll
        for (int b = 0; b < 16; ++b) acc[a][b] = 0.f;

    for (int k0 = 0; k0 < 128; k0 += 32) {
#pragma unroll
        for (int j = 0; j < 4; ++j) {
            int idx = tid * 16 + j * 4;
            int kk = idx >> 7, c = idx & 127;
            *(float4*)&Wt[kk][c] = *(const float4*)&W[(k0 + kk) * 128 + c];
        }
#pragma unroll
        for (int j = 0; j < 4; ++j) {
            int f = tid * 16 + j * 4;
            int r = f >> 5, kk = f & 31;
            int gr = rbase + r;
            float4 v = make_float4(0.f, 0.f, 0.f, 0.f);
            if (gr < n) v = *(const float4*)&h[gr * 128 + k0 + kk];
            Ht[r][kk] = v.x; Ht[r][kk + 1] = v.y; Ht[r][kk + 2] = v.z; Ht[r][kk + 3] = v.w;
        }
        __syncthreads();
#pragma unroll
        for (int kk = 0; kk < 32; ++kk) {
            float wv[16];
#pragma unroll
            for (int j = 0; j < 4; ++j)
                *(float4*)&wv[j * 4] = *(const float4*)&Wt[kk][head * 16 + j * 4];
#pragma unroll
            for (int rr = 0; rr < 4; ++rr) {
                float hv = Ht[r0 + rr * 32][kk];
#pragma unroll
                for (int j = 0; j < 16; ++j) acc[rr][j] = fmaf(hv, wv[j], acc[rr][j]);
            }
        }
        __syncthreads();
    }

    float asv[16], adv[16];
#pragma unroll
    for (int j = 0; j < 16; ++j) { asv[j] = attS[head * 16 + j]; adv[j] = attD[head * 16 + j]; }

#pragma unroll
    for (int rr = 0; rr < 4; ++rr) {
        int r = rbase + r0 + rr * 32;
        if (r < n) {
            float ds = 0.f, dd = 0.f;
#pragma unroll
            for (int j = 0; j < 16; ++j) { ds = fmaf(acc[rr][j], asv[j], ds); dd = fmaf(acc[rr][j], adv[j], dd); }
            als[r * 8 + head] = ds;
            ald[r * 8 + head] = dd;
            unsigned short xb[16];
#pragma unroll
            for (int j = 0; j < 16; ++j) {
                __hip_bfloat16 t = __float2bfloat16(acc[rr][j]);
                xb[j] = *reinterpret_cast<unsigned short*>(&t);
            }
            *(uint4*)&xpb[r * 128 + head * 16]     = *(uint4*)&xb[0];
            *(uint4*)&xpb[r * 128 + head * 16 + 8] = *(uint4*)&xb[8];
        }
    }
}

// ---------------- fused wave-per-node softmax + gather ----------------
// no-max softmax (logits bounded); bf16 xp gather (ushort2 per lane).

__global__ __launch_bounds__(256) void k_agg(
    const unsigned short* __restrict__ xpb, const float* __restrict__ als,
    const float* __restrict__ ald,
    const int* __restrict__ rowptr, const int* __restrict__ colv,
    const float* __restrict__ prev, const float* __restrict__ bias,
    float* __restrict__ y, int n)
{
    __shared__ float alds[4][8][8];   // [wave][edge][head]
    __shared__ int   slds[4][8];      // [wave][edge]
    int wv = threadIdx.x >> 6;
    int wid = (int)((blockIdx.x * blockDim.x + threadIdx.x) >> 6);
    int lane = threadIdx.x & 63;
    if (wid >= n) return;
    int rs = rowptr[wid], re = rowptr[wid + 1];
    int deg = re - rs;

    int hd = lane & 7;
    int ee = lane >> 3;
    float aldn = ald[wid * 8 + hd];

    float sm = 0.f;
    for (int b = ee; b < deg; b += 8) {
        int s = colv[rs + b];
        float v = als[s * 8 + hd] + aldn;
        v = v > 0.f ? v : 0.2f * v;
        sm += expf(v);
    }
    sm += __shfl_xor(sm, 8);
    sm += __shfl_xor(sm, 16);
    sm += __shfl_xor(sm, 32);

    float inv = 1.f / sm;
    int q = lane >> 3;
    int c0 = lane * 2;

    float a0 = 0.f, a1 = 0.f;
    int full = deg & ~7;

    for (int b0 = 0; b0 < full; b0 += 8) {
        int se = colv[rs + b0 + ee];
        float v = als[se * 8 + hd] + aldn;
        v = v > 0.f ? v : 0.2f * v;
        float al = expf(v) * inv;
        alds[wv][ee][hd] = al;
        if (hd == 0) slds[wv][ee] = se;
#pragma unroll
        for (int j = 0; j < 8; ++j) {
            int s = slds[wv][j];
            float a = alds[wv][j][q];
            ushort2 xv = *(const ushort2*)(xpb + (size_t)s * 128 + c0);
            a0 = fmaf(a, bf2f(xv.x), a0);
            a1 = fmaf(a, bf2f(xv.y), a1);
        }
    }

    if (full < deg) {
        int nb = deg - full;
        float al = 0.f;
        int se = 0;
        if (ee < nb) {
            se = colv[rs + full + ee];
            float v = als[se * 8 + hd] + aldn;
            v = v > 0.f ? v : 0.2f * v;
            al = expf(v) * inv;
        }
        alds[wv][ee][hd] = al;
        if (hd == 0) slds[wv][ee] = se;
        for (int j = 0; j < nb; ++j) {
            int s = slds[wv][j];
            float a = alds[wv][j][q];
            ushort2 xv = *(const ushort2*)(xpb + (size_t)s * 128 + c0);
            a0 = fmaf(a, bf2f(xv.x), a0);
            a1 = fmaf(a, bf2f(xv.y), a1);
        }
    }

    float p0 = prev ? prev[wid * 128 + c0] : 0.f;
    float p1 = prev ? prev[wid * 128 + c0 + 1] : 0.f;
    y[wid * 128 + c0] = p0 + a0 + bias[c0];
    y[wid * 128 + c0 + 1] = p1 + a1 + bias[c0 + 1];
}

// ---------------- layernorm over axis 0 ----------------

__global__ __launch_bounds__(256) void k_stats(const float* __restrict__ y,
                                               double* __restrict__ partial, int n) {
    int col = threadIdx.x & 127;
    int rg = threadIdx.x >> 7;
    double s = 0.0, s2 = 0.0;
    for (int r = blockIdx.x * 2 + rg; r < n; r += SWG * 2) {
        float v = y[r * 128 + col];
        s += v; s2 += (double)v * (double)v;
    }
    __shared__ double ls[256], ls2[256];
    ls[threadIdx.x] = s; ls2[threadIdx.x] = s2;
    __syncthreads();
    if (rg == 0) {
        s += ls[threadIdx.x + 128];
        s2 += ls2[threadIdx.x + 128];
        partial[col * SWG + blockIdx.x] = s;
        partial[128 * SWG + col * SWG + blockIdx.x] = s2;
    }
}

__global__ void k_stats_fin(const double* __restrict__ partial, float* __restrict__ stats, int n) {
    int col = threadIdx.x;  // 128 threads
    double s = 0.0, s2 = 0.0;
    for (int w = 0; w < SWG; ++w) {
        s += partial[col * SWG + w];
        s2 += partial[128 * SWG + col * SWG + w];
    }
    double mu = s / n;
    double var = s2 / n - mu * mu;
    stats[col] = (float)mu;
    stats[128 + col] = (float)(1.0 / sqrt(var + 1e-5));
}

__global__ __launch_bounds__(256) void k_elem(const float* __restrict__ y,
                                              const float* __restrict__ stats,
                                              const float* __restrict__ gamma,
                                              const float* __restrict__ beta,
                                              float* __restrict__ out, int total)
{
    int i = blockIdx.x * blockDim.x + threadIdx.x;
    if (i >= total) return;
    int col = i & 127;
    float v = (y[i] - stats[col]) * stats[128 + col] * gamma[col] + beta[col];
    out[i] = v > 0.f ? v : expm1f(v);
}

// ---------------- pooling: split stage + reduce/readout ----------------

__global__ __launch_bounds__(256) void k_pool_part(
    const float* __restrict__ h, const void* __restrict__ batch,
    const int* __restrict__ flag, float* __restrict__ ppart, int n)
{
    int g = blockIdx.x / PSP;
    int sp = blockIdx.x % PSP;
    int is64 = flag[0];
    int lo = 0, hi = n;
    while (lo < hi) { int mid = (lo + hi) >> 1; if (geti(batch, mid, is64) < g) lo = mid + 1; else hi = mid; }
    int start = lo;
    hi = n;
    while (lo < hi) { int mid = (lo + hi) >> 1; if (geti(batch, mid, is64) < g + 1) lo = mid + 1; else hi = mid; }
    int end = lo;
    int cnt = end - start;
    int slice = (cnt + PSP - 1) / PSP;
    int s0 = start + sp * slice;
    int s1 = s0 + slice; if (s1 > end) s1 = end;

    int col = threadIdx.x & 127;
    int half = threadIdx.x >> 7;
    float s = 0.f;
    for (int r = s0 + half; r < s1; r += 2) s += h[r * 128 + col];
    __shared__ float ls[256];
    ls[threadIdx.x] = s;
    __syncthreads();
    if (half == 0) ppart[(g * PSP + sp) * 128 + col] = s + ls[col + 128];
}

__global__ __launch_bounds__(128) void k_pool_fin(
    const float* __restrict__ ppart, const void* __restrict__ batch,
    const int* __restrict__ flag, const float* __restrict__ row,
    const float* __restrict__ rob, float* __restrict__ out, int n)
{
    int g = blockIdx.x;
    int is64 = flag[0];
    int lo = 0, hi = n;
    while (lo < hi) { int mid = (lo + hi) >> 1; if (geti(batch, mid, is64) < g) lo = mid + 1; else hi = mid; }
    int start = lo;
    hi = n;
    while (lo < hi) { int mid = (lo + hi) >> 1; if (geti(batch, mid, is64) < g + 1) lo = mid + 1; else hi = mid; }
    int cnt = lo - start;

    int col = threadIdx.x;   // 128
    float s = 0.f;
#pragma unroll
    for (int sp = 0; sp < PSP; ++sp) s += ppart[(g * PSP + sp) * 128 + col];
    __shared__ float ls[128];
    ls[col] = s * (1.f / fmaxf((float)cnt, 1.f));
    __syncthreads();
    if (col < 2) {
        float acc = 0.f;
        for (int c = 0; c < 128; ++c) acc = fmaf(ls[c], row[c * 2 + col], acc);
        out[g * 2 + col] = acc + rob[col];
    }
}

// ---------------- launch ----------------

extern "C" void kernel_launch(void* const* d_in, const int* in_sizes, int n_in,
                              void* d_out, int out_size, void* d_ws, size_t ws_size,
                              hipStream_t stream) {
    const float* x     = (const float*)d_in[0];
    const void*  ei    = d_in[1];
    const void*  batch = d_in[2];
    const float* W     = (const float*)d_in[3];
    const float* attS  = (const float*)d_in[4];
    const float* attD  = (const float*)d_in[5];
    const float* bias  = (const float*)d_in[6];
    const float* gamma = (const float*)d_in[7];
    const float* beta  = (const float*)d_in[8];
    const float* row   = (const float*)d_in[9];
    const float* rob   = (const float*)d_in[10];
    float* out = (float*)d_out;

    char* wsb = (char*)d_ws;
    size_t off = 0;
    auto alloc = [&](size_t bytes) {
        void* p = wsb + off;
        off += (bytes + 255) & ~(size_t)255;
        return p;
    };
    int*    flag    = (int*)alloc(256);
    int*    rowptr  = (int*)alloc((size_t)(NN + 1) * 4);
    int*    cnts    = (int*)alloc((size_t)NN * 4 * 2);   // counts + fill
    int*    bsum    = (int*)alloc((size_t)256 * 4);
    int*    colv    = (int*)alloc((size_t)MM * 4);
    double* partial = (double*)alloc((size_t)128 * SWG * 2 * 8);
    float*  stats   = (float*)alloc(256 * 4);
    float*  ppart   = (float*)alloc((size_t)GG * PSP * 128 * 4);
    float*  ALS     = (float*)alloc((size_t)NN * 8 * 4);
    float*  ALD     = (float*)alloc((size_t)NN * 8 * 4);
    unsigned short* XPB = (unsigned short*)alloc((size_t)NN * 128 * 2);
    float* Y   = (float*)alloc((size_t)NN * 128 * 4);
    float* HB1 = (float*)alloc((size_t)NN * 128 * 4);
    float* HB2 = (float*)alloc((size_t)NN * 128 * 4);
    float* H3  = (float*)alloc((size_t)NN * 128 * 4);
    (void)ws_size; (void)in_sizes; (void)n_in; (void)out_size;

    int* fill = cnts + NN;
    const int GE = (NN * 128 + 255) / 256;

    hipLaunchKernelGGL(k_detect, dim3(1), dim3(64), 0, stream, (const int*)ei, flag);
    hipLaunchKernelGGL(k_zero, dim3((2 * NN + 255) / 256), dim3(256), 0, stream, cnts, 2 * NN);
    hipLaunchKernelGGL(k_count, dim3((MM + 255) / 256), dim3(256), 0, stream, ei, flag, cnts);
    hipLaunchKernelGGL(k_scan1, dim3(NSB), dim3(256), 0, stream, cnts, rowptr, bsum);
    hipLaunchKernelGGL(k_scan2, dim3(1), dim3(256), 0, stream, bsum);
    hipLaunchKernelGGL(k_scan3, dim3(NSB), dim3(256), 0, stream, rowptr, bsum);
    hipLaunchKernelGGL(k_fill, dim3((MM + 255) / 256), dim3(256), 0, stream, ei, flag, rowptr, fill, colv);

    // h chain: inputs {x, HB1, HB2}, outputs {HB1, HB2, H3}
    const float* hs[4] = { x, HB1, HB2, H3 };
    for (int b = 0; b < 3; ++b) {
        const float* h = hs[b];
        const float* prev = (b == 0) ? nullptr : hs[b - 1];
        float* hn = (float*)hs[b + 1];

        hipLaunchKernelGGL(k_gemm_att, dim3((NN + 127) / 128), dim3(256), 0, stream,
                           h, W + b * 16384, attS + b * 128, attD + b * 128, XPB, ALS, ALD, NN);
        hipLaunchKernelGGL(k_agg, dim3((NN + 3) / 4), dim3(256), 0, stream,
                           XPB, ALS, ALD, rowptr, colv, prev, bias + b * 128, Y, NN);
        hipLaunchKernelGGL(k_stats, dim3(SWG), dim3(256), 0, stream, Y, partial, NN);
        hipLaunchKernelGGL(k_stats_fin, dim3(1), dim3(128), 0, stream, partial, stats, NN);
        hipLaunchKernelGGL(k_elem, dim3(GE), dim3(256), 0, stream,
                           Y, stats, gamma + b * 128, beta + b * 128, hn, NN * 128);
    }

    hipLaunchKernelGGL(k_pool_part, dim3(GG * PSP), dim3(256), 0, stream,
                       hs[3], batch, flag, ppart, NN);
    hipLaunchKernelGGL(k_pool_fin, dim3(GG), dim3(128), 0, stream,
                       ppart, batch, flag, row, rob, out, NN);
}

// Round 15
// 551.039 us; speedup vs baseline: 3.6262x; 1.0554x over previous
//
#include <hip/hip_runtime.h>
#include <hip/hip_bf16.h>
#include <math.h>

#define NN 50000
#define EE 800000
#define MM (EE + NN)   // edges + self loops
#define GG 64
#define SWG 512        // stat partial workgroups
#define NSB ((NN + 255) / 256)   // scan blocks = 196
#define PSP 16         // pooling splits per group

// adaptive int read: handles both int32 and int64 device buffers
__device__ __forceinline__ int geti(const void* p, long idx, int is64) {
    return is64 ? (int)((const long long*)p)[idx] : ((const int*)p)[idx];
}

__device__ __forceinline__ float bf2f(unsigned short u) {
    return __uint_as_float(((unsigned)u) << 16);
}

__device__ __forceinline__ float eluf(float z) {
    return z > 0.f ? z : expm1f(z);
}

// int64 little-endian values < 2^31: odd int32 words are all zero.
__global__ void k_detect(const int* __restrict__ ei, int* __restrict__ flag) {
    if (blockIdx.x == 0 && threadIdx.x == 0) {
        int ok = 1;
        for (int k = 0; k < 128; ++k) {
            int lo = ei[2 * k], hi = ei[2 * k + 1];
            if (hi != 0 || (unsigned)lo >= (unsigned)NN) { ok = 0; break; }
        }
        flag[0] = ok;
    }
}

// ---------------- CSR by destination ----------------

__global__ void k_zero(int* p, int n) {
    int i = blockIdx.x * blockDim.x + threadIdx.x;
    if (i < n) p[i] = 0;
}

__global__ void k_count(const void* __restrict__ ei, const int* __restrict__ flag,
                        int* __restrict__ counts) {
    int e = blockIdx.x * blockDim.x + threadIdx.x;
    if (e >= MM) return;
    int is64 = flag[0];
    int d = (e < EE) ? geti(ei, (long)EE + e, is64) : (e - EE);
    if ((unsigned)d < (unsigned)NN) atomicAdd(&counts[d], 1);
}

// parallel scan: per-block inclusive scan + block sums
__global__ __launch_bounds__(256) void k_scan1(const int* __restrict__ counts,
                                               int* __restrict__ rowptr,
                                               int* __restrict__ bsum) {
    __shared__ int buf[256];
    int b = blockIdx.x, tid = threadIdx.x;
    int i = b * 256 + tid;
    int v = (i < NN) ? counts[i] : 0;
    buf[tid] = v;
    __syncthreads();
    for (int off = 1; off < 256; off <<= 1) {
        int t = (tid >= off) ? buf[tid - off] : 0;
        __syncthreads();
        buf[tid] += t;
        __syncthreads();
    }
    if (i < NN) rowptr[i + 1] = buf[tid];
    if (tid == 255) bsum[b] = buf[255];
}

__global__ __launch_bounds__(256) void k_scan2(int* __restrict__ bsum) {
    __shared__ int buf[256];
    int tid = threadIdx.x;
    int v = (tid < NSB) ? bsum[tid] : 0;
    buf[tid] = v;
    __syncthreads();
    for (int off = 1; off < 256; off <<= 1) {
        int t = (tid >= off) ? buf[tid - off] : 0;
        __syncthreads();
        buf[tid] += t;
        __syncthreads();
    }
    if (tid < NSB) bsum[tid] = (tid == 0) ? 0 : buf[tid - 1];
}

__global__ __launch_bounds__(256) void k_scan3(int* __restrict__ rowptr,
                                               const int* __restrict__ bsum) {
    int b = blockIdx.x, tid = threadIdx.x;
    int i = b * 256 + tid;
    if (i < NN) rowptr[i + 1] += bsum[b];
    if (b == 0 && tid == 0) rowptr[0] = 0;
}

__global__ void k_fill(const void* __restrict__ ei, const int* __restrict__ flag,
                       const int* __restrict__ rowptr,
                       int* __restrict__ fill, int* __restrict__ colv) {
    int e = blockIdx.x * blockDim.x + threadIdx.x;
    if (e >= MM) return;
    int is64 = flag[0];
    int s, d;
    if (e < EE) { s = geti(ei, e, is64); d = geti(ei, (long)EE + e, is64); }
    else { s = d = e - EE; }
    if ((unsigned)d >= (unsigned)NN || (unsigned)s >= (unsigned)NN) return;
    int pos = rowptr[d] + atomicAdd(&fill[d], 1);
    if ((unsigned)pos < (unsigned)MM) colv[pos] = s;
}

// ---------------- fused tiled GEMM + attention dots (bf16 xp out) ----------------
// h input either raw (hsrc) or computed on the fly as elu(Y*sc+sh) from (Ysrc, st).

__global__ __launch_bounds__(256) void k_gemm_att(
    const float* __restrict__ hsrc, const float* __restrict__ Ysrc,
    const float* __restrict__ st, const float* __restrict__ W,
    const float* __restrict__ attS, const float* __restrict__ attD,
    unsigned short* __restrict__ xpb, float* __restrict__ als,
    float* __restrict__ ald, int n)
{
    __shared__ float Wt[32][128];
    __shared__ float Ht[128][33];
    int tid = threadIdx.x;
    int head = tid & 7, r0 = tid >> 3;
    int rbase = blockIdx.x * 128;
    bool useY = (Ysrc != nullptr);

    float acc[4][16];
#pragma unroll
    for (int a = 0; a < 4; ++a)
#pragma unroll
        for (int b = 0; b < 16; ++b) acc[a][b] = 0.f;

    for (int k0 = 0; k0 < 128; k0 += 32) {
#pragma unroll
        for (int j = 0; j < 4; ++j) {
            int idx = tid * 16 + j * 4;
            int kk = idx >> 7, c = idx & 127;
            *(float4*)&Wt[kk][c] = *(const float4*)&W[(k0 + kk) * 128 + c];
        }
#pragma unroll
        for (int j = 0; j < 4; ++j) {
            int f = tid * 16 + j * 4;
            int r = f >> 5, kk = f & 31;
            int gr = rbase + r;
            float4 v = make_float4(0.f, 0.f, 0.f, 0.f);
            if (gr < n) {
                if (useY) {
                    float4 yv = *(const float4*)&Ysrc[gr * 128 + k0 + kk];
                    float4 scv = *(const float4*)&st[k0 + kk];
                    float4 shv = *(const float4*)&st[128 + k0 + kk];
                    v.x = eluf(fmaf(yv.x, scv.x, shv.x));
                    v.y = eluf(fmaf(yv.y, scv.y, shv.y));
                    v.z = eluf(fmaf(yv.z, scv.z, shv.z));
                    v.w = eluf(fmaf(yv.w, scv.w, shv.w));
                } else {
                    v = *(const float4*)&hsrc[gr * 128 + k0 + kk];
                }
            }
            Ht[r][kk] = v.x; Ht[r][kk + 1] = v.y; Ht[r][kk + 2] = v.z; Ht[r][kk + 3] = v.w;
        }
        __syncthreads();
#pragma unroll
        for (int kk = 0; kk < 32; ++kk) {
            float wv[16];
#pragma unroll
            for (int j = 0; j < 4; ++j)
                *(float4*)&wv[j * 4] = *(const float4*)&Wt[kk][head * 16 + j * 4];
#pragma unroll
            for (int rr = 0; rr < 4; ++rr) {
                float hv = Ht[r0 + rr * 32][kk];
#pragma unroll
                for (int j = 0; j < 16; ++j) acc[rr][j] = fmaf(hv, wv[j], acc[rr][j]);
            }
        }
        __syncthreads();
    }

    float asv[16], adv[16];
#pragma unroll
    for (int j = 0; j < 16; ++j) { asv[j] = attS[head * 16 + j]; adv[j] = attD[head * 16 + j]; }

#pragma unroll
    for (int rr = 0; rr < 4; ++rr) {
        int r = rbase + r0 + rr * 32;
        if (r < n) {
            float ds = 0.f, dd = 0.f;
#pragma unroll
            for (int j = 0; j < 16; ++j) { ds = fmaf(acc[rr][j], asv[j], ds); dd = fmaf(acc[rr][j], adv[j], dd); }
            als[r * 8 + head] = ds;
            ald[r * 8 + head] = dd;
            unsigned short xb[16];
#pragma unroll
            for (int j = 0; j < 16; ++j) {
                __hip_bfloat16 t = __float2bfloat16(acc[rr][j]);
                xb[j] = *reinterpret_cast<unsigned short*>(&t);
            }
            *(uint4*)&xpb[r * 128 + head * 16]     = *(uint4*)&xb[0];
            *(uint4*)&xpb[r * 128 + head * 16 + 8] = *(uint4*)&xb[8];
        }
    }
}

// ---------------- fused wave-per-node softmax + gather ----------------
// no-max softmax (logits bounded); bf16 xp gather; prev term either raw
// (prevRaw) or computed on the fly from (prevY, pst).

__global__ __launch_bounds__(256) void k_agg(
    const unsigned short* __restrict__ xpb, const float* __restrict__ als,
    const float* __restrict__ ald,
    const int* __restrict__ rowptr, const int* __restrict__ colv,
    const float* __restrict__ prevRaw, const float* __restrict__ prevY,
    const float* __restrict__ pst, const float* __restrict__ bias,
    float* __restrict__ y, int n)
{
    __shared__ float alds[4][8][8];   // [wave][edge][head]
    __shared__ int   slds[4][8];      // [wave][edge]
    int wv = threadIdx.x >> 6;
    int wid = (int)((blockIdx.x * blockDim.x + threadIdx.x) >> 6);
    int lane = threadIdx.x & 63;
    if (wid >= n) return;
    int rs = rowptr[wid], re = rowptr[wid + 1];
    int deg = re - rs;

    int hd = lane & 7;
    int ee = lane >> 3;
    float aldn = ald[wid * 8 + hd];

    float sm = 0.f;
    for (int b = ee; b < deg; b += 8) {
        int s = colv[rs + b];
        float v = als[s * 8 + hd] + aldn;
        v = v > 0.f ? v : 0.2f * v;
        sm += expf(v);
    }
    sm += __shfl_xor(sm, 8);
    sm += __shfl_xor(sm, 16);
    sm += __shfl_xor(sm, 32);

    float inv = 1.f / sm;
    int q = lane >> 3;
    int c0 = lane * 2;

    float a0 = 0.f, a1 = 0.f;
    int full = deg & ~7;

    for (int b0 = 0; b0 < full; b0 += 8) {
        int se = colv[rs + b0 + ee];
        float v = als[se * 8 + hd] + aldn;
        v = v > 0.f ? v : 0.2f * v;
        float al = expf(v) * inv;
        alds[wv][ee][hd] = al;
        if (hd == 0) slds[wv][ee] = se;
#pragma unroll
        for (int j = 0; j < 8; ++j) {
            int s = slds[wv][j];
            float a = alds[wv][j][q];
            ushort2 xv = *(const ushort2*)(xpb + (size_t)s * 128 + c0);
            a0 = fmaf(a, bf2f(xv.x), a0);
            a1 = fmaf(a, bf2f(xv.y), a1);
        }
    }

    if (full < deg) {
        int nb = deg - full;
        float al = 0.f;
        int se = 0;
        if (ee < nb) {
            se = colv[rs + full + ee];
            float v = als[se * 8 + hd] + aldn;
            v = v > 0.f ? v : 0.2f * v;
            al = expf(v) * inv;
        }
        alds[wv][ee][hd] = al;
        if (hd == 0) slds[wv][ee] = se;
        for (int j = 0; j < nb; ++j) {
            int s = slds[wv][j];
            float a = alds[wv][j][q];
            ushort2 xv = *(const ushort2*)(xpb + (size_t)s * 128 + c0);
            a0 = fmaf(a, bf2f(xv.x), a0);
            a1 = fmaf(a, bf2f(xv.y), a1);
        }
    }

    float p0 = 0.f, p1 = 0.f;
    if (prevY) {
        float2 yv = *(const float2*)(prevY + (size_t)wid * 128 + c0);
        p0 = eluf(fmaf(yv.x, pst[c0], pst[128 + c0]));
        p1 = eluf(fmaf(yv.y, pst[c0 + 1], pst[129 + c0]));
    } else if (prevRaw) {
        p0 = prevRaw[(size_t)wid * 128 + c0];
        p1 = prevRaw[(size_t)wid * 128 + c0 + 1];
    }
    y[wid * 128 + c0] = p0 + a0 + bias[c0];
    y[wid * 128 + c0 + 1] = p1 + a1 + bias[c0 + 1];
}

// ---------------- layernorm over axis 0 ----------------

__global__ __launch_bounds__(256) void k_stats(const float* __restrict__ y,
                                               double* __restrict__ partial, int n) {
    int col = threadIdx.x & 127;
    int rg = threadIdx.x >> 7;
    double s = 0.0, s2 = 0.0;
    for (int r = blockIdx.x * 2 + rg; r < n; r += SWG * 2) {
        float v = y[r * 128 + col];
        s += v; s2 += (double)v * (double)v;
    }
    __shared__ double ls[256], ls2[256];
    ls[threadIdx.x] = s; ls2[threadIdx.x] = s2;
    __syncthreads();
    if (rg == 0) {
        s += ls[threadIdx.x + 128];
        s2 += ls2[threadIdx.x + 128];
        partial[col * SWG + blockIdx.x] = s;
        partial[128 * SWG + col * SWG + blockIdx.x] = s2;
    }
}

// finishes stats AND bakes gamma/beta into affine scale/shift:
// st[col] = gamma*rsig, st[128+col] = beta - mu*gamma*rsig
__global__ void k_stats_fin(const double* __restrict__ partial,
                            const float* __restrict__ gamma,
                            const float* __restrict__ beta,
                            float* __restrict__ st, int n) {
    int col = threadIdx.x;  // 128 threads
    double s = 0.0, s2 = 0.0;
    for (int w = 0; w < SWG; ++w) {
        s += partial[col * SWG + w];
        s2 += partial[128 * SWG + col * SWG + w];
    }
    double mu = s / n;
    double var = s2 / n - mu * mu;
    double rsig = 1.0 / sqrt(var + 1e-5);
    double sc = (double)gamma[col] * rsig;
    st[col] = (float)sc;
    st[128 + col] = (float)((double)beta[col] - mu * sc);
}

// ---------------- pooling: split stage + reduce/readout ----------------
// stage 1 applies elu(Y*sc+sh) on the fly.

__global__ __launch_bounds__(256) void k_pool_part(
    const float* __restrict__ Y, const float* __restrict__ st,
    const void* __restrict__ batch, const int* __restrict__ flag,
    float* __restrict__ ppart, int n)
{
    int g = blockIdx.x / PSP;
    int sp = blockIdx.x % PSP;
    int is64 = flag[0];
    int lo = 0, hi = n;
    while (lo < hi) { int mid = (lo + hi) >> 1; if (geti(batch, mid, is64) < g) lo = mid + 1; else hi = mid; }
    int start = lo;
    hi = n;
    while (lo < hi) { int mid = (lo + hi) >> 1; if (geti(batch, mid, is64) < g + 1) lo = mid + 1; else hi = mid; }
    int end = lo;
    int cnt = end - start;
    int slice = (cnt + PSP - 1) / PSP;
    int s0 = start + sp * slice;
    int s1 = s0 + slice; if (s1 > end) s1 = end;

    int col = threadIdx.x & 127;
    int half = threadIdx.x >> 7;
    float sc = st[col], sh = st[128 + col];
    float s = 0.f;
    for (int r = s0 + half; r < s1; r += 2)
        s += eluf(fmaf(Y[(size_t)r * 128 + col], sc, sh));
    __shared__ float ls[256];
    ls[threadIdx.x] = s;
    __syncthreads();
    if (half == 0) ppart[(g * PSP + sp) * 128 + col] = s + ls[col + 128];
}

__global__ __launch_bounds__(128) void k_pool_fin(
    const float* __restrict__ ppart, const void* __restrict__ batch,
    const int* __restrict__ flag, const float* __restrict__ row,
    const float* __restrict__ rob, float* __restrict__ out, int n)
{
    int g = blockIdx.x;
    int is64 = flag[0];
    int lo = 0, hi = n;
    while (lo < hi) { int mid = (lo + hi) >> 1; if (geti(batch, mid, is64) < g) lo = mid + 1; else hi = mid; }
    int start = lo;
    hi = n;
    while (lo < hi) { int mid = (lo + hi) >> 1; if (geti(batch, mid, is64) < g + 1) lo = mid + 1; else hi = mid; }
    int cnt = lo - start;

    int col = threadIdx.x;   // 128
    float s = 0.f;
#pragma unroll
    for (int sp = 0; sp < PSP; ++sp) s += ppart[(g * PSP + sp) * 128 + col];
    __shared__ float ls[128];
    ls[col] = s * (1.f / fmaxf((float)cnt, 1.f));
    __syncthreads();
    if (col < 2) {
        float acc = 0.f;
        for (int c = 0; c < 128; ++c) acc = fmaf(ls[c], row[c * 2 + col], acc);
        out[g * 2 + col] = acc + rob[col];
    }
}

// ---------------- launch ----------------

extern "C" void kernel_launch(void* const* d_in, const int* in_sizes, int n_in,
                              void* d_out, int out_size, void* d_ws, size_t ws_size,
                              hipStream_t stream) {
    const float* x     = (const float*)d_in[0];
    const void*  ei    = d_in[1];
    const void*  batch = d_in[2];
    const float* W     = (const float*)d_in[3];
    const float* attS  = (const float*)d_in[4];
    const float* attD  = (const float*)d_in[5];
    const float* bias  = (const float*)d_in[6];
    const float* gamma = (const float*)d_in[7];
    const float* beta  = (const float*)d_in[8];
    const float* row   = (const float*)d_in[9];
    const float* rob   = (const float*)d_in[10];
    float* out = (float*)d_out;

    char* wsb = (char*)d_ws;
    size_t off = 0;
    auto alloc = [&](size_t bytes) {
        void* p = wsb + off;
        off += (bytes + 255) & ~(size_t)255;
        return p;
    };
    int*    flag    = (int*)alloc(256);
    int*    rowptr  = (int*)alloc((size_t)(NN + 1) * 4);
    int*    cnts    = (int*)alloc((size_t)NN * 4 * 2);   // counts + fill
    int*    bsum    = (int*)alloc((size_t)256 * 4);
    int*    colv    = (int*)alloc((size_t)MM * 4);
    double* partial = (double*)alloc((size_t)128 * SWG * 2 * 8);
    float*  st1     = (float*)alloc(256 * 4);
    float*  st2     = (float*)alloc(256 * 4);
    float*  st3     = (float*)alloc(256 * 4);
    float*  ppart   = (float*)alloc((size_t)GG * PSP * 128 * 4);
    float*  ALS     = (float*)alloc((size_t)NN * 8 * 4);
    float*  ALD     = (float*)alloc((size_t)NN * 8 * 4);
    unsigned short* XPB = (unsigned short*)alloc((size_t)NN * 128 * 2);
    float* Y1 = (float*)alloc((size_t)NN * 128 * 4);
    float* Y2 = (float*)alloc((size_t)NN * 128 * 4);
    float* Y3 = (float*)alloc((size_t)NN * 128 * 4);
    (void)ws_size; (void)in_sizes; (void)n_in; (void)out_size;

    int* fill = cnts + NN;
    const int GB = (NN + 127) / 128;   // gemm blocks
    const int GA = (NN + 3) / 4;       // agg blocks

    hipLaunchKernelGGL(k_detect, dim3(1), dim3(64), 0, stream, (const int*)ei, flag);
    hipLaunchKernelGGL(k_zero, dim3((2 * NN + 255) / 256), dim3(256), 0, stream, cnts, 2 * NN);
    hipLaunchKernelGGL(k_count, dim3((MM + 255) / 256), dim3(256), 0, stream, ei, flag, cnts);
    hipLaunchKernelGGL(k_scan1, dim3(NSB), dim3(256), 0, stream, cnts, rowptr, bsum);
    hipLaunchKernelGGL(k_scan2, dim3(1), dim3(256), 0, stream, bsum);
    hipLaunchKernelGGL(k_scan3, dim3(NSB), dim3(256), 0, stream, rowptr, bsum);
    hipLaunchKernelGGL(k_fill, dim3((MM + 255) / 256), dim3(256), 0, stream, ei, flag, rowptr, fill, colv);

    // ---- layer 0: h = x (raw), prev = 0 ----
    hipLaunchKernelGGL(k_gemm_att, dim3(GB), dim3(256), 0, stream,
                       x, (const float*)nullptr, (const float*)nullptr,
                       W, attS, attD, XPB, ALS, ALD, NN);
    hipLaunchKernelGGL(k_agg, dim3(GA), dim3(256), 0, stream,
                       XPB, ALS, ALD, rowptr, colv,
                       (const float*)nullptr, (const float*)nullptr, (const float*)nullptr,
                       bias, Y1, NN);
    hipLaunchKernelGGL(k_stats, dim3(SWG), dim3(256), 0, stream, Y1, partial, NN);
    hipLaunchKernelGGL(k_stats_fin, dim3(1), dim3(128), 0, stream, partial, gamma, beta, st1, NN);

    // ---- layer 1: h = E1(Y1), prev = x (raw) ----
    hipLaunchKernelGGL(k_gemm_att, dim3(GB), dim3(256), 0, stream,
                       (const float*)nullptr, Y1, st1,
                       W + 16384, attS + 128, attD + 128, XPB, ALS, ALD, NN);
    hipLaunchKernelGGL(k_agg, dim3(GA), dim3(256), 0, stream,
                       XPB, ALS, ALD, rowptr, colv,
                       x, (const float*)nullptr, (const float*)nullptr,
                       bias + 128, Y2, NN);
    hipLaunchKernelGGL(k_stats, dim3(SWG), dim3(256), 0, stream, Y2, partial, NN);
    hipLaunchKernelGGL(k_stats_fin, dim3(1), dim3(128), 0, stream, partial, gamma + 128, beta + 128, st2, NN);

    // ---- layer 2: h = E2(Y2), prev = E1(Y1) ----
    hipLaunchKernelGGL(k_gemm_att, dim3(GB), dim3(256), 0, stream,
                       (const float*)nullptr, Y2, st2,
                       W + 32768, attS + 256, attD + 256, XPB, ALS, ALD, NN);
    hipLaunchKernelGGL(k_agg, dim3(GA), dim3(256), 0, stream,
                       XPB, ALS, ALD, rowptr, colv,
                       (const float*)nullptr, Y1, st1,
                       bias + 256, Y3, NN);
    hipLaunchKernelGGL(k_stats, dim3(SWG), dim3(256), 0, stream, Y3, partial, NN);
    hipLaunchKernelGGL(k_stats_fin, dim3(1), dim3(128), 0, stream, partial, gamma + 256, beta + 256, st3, NN);

    // ---- pooling on E3(Y3) ----
    hipLaunchKernelGGL(k_pool_part, dim3(GG * PSP), dim3(256), 0, stream,
                       Y3, st3, batch, flag, ppart, NN);
    hipLaunchKernelGGL(k_pool_fin, dim3(GG), dim3(128), 0, stream,
                       ppart, batch, flag, row, rob, out, NN);
}

// Round 16
// 532.049 us; speedup vs baseline: 3.7557x; 1.0357x over previous
//
#include <hip/hip_runtime.h>
#include <hip/hip_bf16.h>
#include <math.h>

#define NN 50000
#define EE 800000
#define MM (EE + NN)   // edges + self loops
#define GG 64
#define SWG 512        // stat partial workgroups
#define NSB ((NN + 255) / 256)   // scan blocks = 196
#define PSP 16         // pooling splits per group

// adaptive int read: handles both int32 and int64 device buffers
__device__ __forceinline__ int geti(const void* p, long idx, int is64) {
    return is64 ? (int)((const long long*)p)[idx] : ((const int*)p)[idx];
}

__device__ __forceinline__ float bf2f(unsigned short u) {
    return __uint_as_float(((unsigned)u) << 16);
}

__device__ __forceinline__ float eluf(float z) {
    return z > 0.f ? z : expm1f(z);
}

// int64 little-endian values < 2^31: odd int32 words are all zero.
__global__ void k_detect(const int* __restrict__ ei, int* __restrict__ flag) {
    if (blockIdx.x == 0 && threadIdx.x == 0) {
        int ok = 1;
        for (int k = 0; k < 128; ++k) {
            int lo = ei[2 * k], hi = ei[2 * k + 1];
            if (hi != 0 || (unsigned)lo >= (unsigned)NN) { ok = 0; break; }
        }
        flag[0] = ok;
    }
}

// ---------------- CSR by destination ----------------

__global__ void k_zero(int* p, int n) {
    int i = blockIdx.x * blockDim.x + threadIdx.x;
    if (i < n) p[i] = 0;
}

__global__ void k_count(const void* __restrict__ ei, const int* __restrict__ flag,
                        int* __restrict__ counts) {
    int e = blockIdx.x * blockDim.x + threadIdx.x;
    if (e >= MM) return;
    int is64 = flag[0];
    int d = (e < EE) ? geti(ei, (long)EE + e, is64) : (e - EE);
    if ((unsigned)d < (unsigned)NN) atomicAdd(&counts[d], 1);
}

// parallel scan: per-block inclusive scan + block sums
__global__ __launch_bounds__(256) void k_scan1(const int* __restrict__ counts,
                                               int* __restrict__ rowptr,
                                               int* __restrict__ bsum) {
    __shared__ int buf[256];
    int b = blockIdx.x, tid = threadIdx.x;
    int i = b * 256 + tid;
    int v = (i < NN) ? counts[i] : 0;
    buf[tid] = v;
    __syncthreads();
    for (int off = 1; off < 256; off <<= 1) {
        int t = (tid >= off) ? buf[tid - off] : 0;
        __syncthreads();
        buf[tid] += t;
        __syncthreads();
    }
    if (i < NN) rowptr[i + 1] = buf[tid];
    if (tid == 255) bsum[b] = buf[255];
}

__global__ __launch_bounds__(256) void k_scan2(int* __restrict__ bsum) {
    __shared__ int buf[256];
    int tid = threadIdx.x;
    int v = (tid < NSB) ? bsum[tid] : 0;
    buf[tid] = v;
    __syncthreads();
    for (int off = 1; off < 256; off <<= 1) {
        int t = (tid >= off) ? buf[tid - off] : 0;
        __syncthreads();
        buf[tid] += t;
        __syncthreads();
    }
    if (tid < NSB) bsum[tid] = (tid == 0) ? 0 : buf[tid - 1];
}

__global__ __launch_bounds__(256) void k_scan3(int* __restrict__ rowptr,
                                               const int* __restrict__ bsum) {
    int b = blockIdx.x, tid = threadIdx.x;
    int i = b * 256 + tid;
    if (i < NN) rowptr[i + 1] += bsum[b];
    if (b == 0 && tid == 0) rowptr[0] = 0;
}

__global__ void k_fill(const void* __restrict__ ei, const int* __restrict__ flag,
                       const int* __restrict__ rowptr,
                       int* __restrict__ fill, int* __restrict__ colv) {
    int e = blockIdx.x * blockDim.x + threadIdx.x;
    if (e >= MM) return;
    int is64 = flag[0];
    int s, d;
    if (e < EE) { s = geti(ei, e, is64); d = geti(ei, (long)EE + e, is64); }
    else { s = d = e - EE; }
    if ((unsigned)d >= (unsigned)NN || (unsigned)s >= (unsigned)NN) return;
    int pos = rowptr[d] + atomicAdd(&fill[d], 1);
    if ((unsigned)pos < (unsigned)MM) colv[pos] = s;
}

// ---------------- fused tiled GEMM + attention dots (bf16 xp out) ----------------
// h input either raw (hsrc) or computed on the fly as elu(Y*sc+sh) from (Ysrc, st).

__global__ __launch_bounds__(256) void k_gemm_att(
    const float* __restrict__ hsrc, const float* __restrict__ Ysrc,
    const float* __restrict__ st, const float* __restrict__ W,
    const float* __restrict__ attS, const float* __restrict__ attD,
    unsigned short* __restrict__ xpb, float* __restrict__ als,
    float* __restrict__ ald, int n)
{
    __shared__ float Wt[32][128];
    __shared__ float Ht[128][33];
    int tid = threadIdx.x;
    int head = tid & 7, r0 = tid >> 3;
    int rbase = blockIdx.x * 128;
    bool useY = (Ysrc != nullptr);

    float acc[4][16];
#pragma unroll
    for (int a = 0; a < 4; ++a)
#pragma unroll
        for (int b = 0; b < 16; ++b) acc[a][b] = 0.f;

    for (int k0 = 0; k0 < 128; k0 += 32) {
#pragma unroll
        for (int j = 0; j < 4; ++j) {
            int idx = tid * 16 + j * 4;
            int kk = idx >> 7, c = idx & 127;
            *(float4*)&Wt[kk][c] = *(const float4*)&W[(k0 + kk) * 128 + c];
        }
#pragma unroll
        for (int j = 0; j < 4; ++j) {
            int f = tid * 16 + j * 4;
            int r = f >> 5, kk = f & 31;
            int gr = rbase + r;
            float4 v = make_float4(0.f, 0.f, 0.f, 0.f);
            if (gr < n) {
                if (useY) {
                    float4 yv = *(const float4*)&Ysrc[gr * 128 + k0 + kk];
                    float4 scv = *(const float4*)&st[k0 + kk];
                    float4 shv = *(const float4*)&st[128 + k0 + kk];
                    v.x = eluf(fmaf(yv.x, scv.x, shv.x));
                    v.y = eluf(fmaf(yv.y, scv.y, shv.y));
                    v.z = eluf(fmaf(yv.z, scv.z, shv.z));
                    v.w = eluf(fmaf(yv.w, scv.w, shv.w));
                } else {
                    v = *(const float4*)&hsrc[gr * 128 + k0 + kk];
                }
            }
            Ht[r][kk] = v.x; Ht[r][kk + 1] = v.y; Ht[r][kk + 2] = v.z; Ht[r][kk + 3] = v.w;
        }
        __syncthreads();
#pragma unroll
        for (int kk = 0; kk < 32; ++kk) {
            float wv[16];
#pragma unroll
            for (int j = 0; j < 4; ++j)
                *(float4*)&wv[j * 4] = *(const float4*)&Wt[kk][head * 16 + j * 4];
#pragma unroll
            for (int rr = 0; rr < 4; ++rr) {
                float hv = Ht[r0 + rr * 32][kk];
#pragma unroll
                for (int j = 0; j < 16; ++j) acc[rr][j] = fmaf(hv, wv[j], acc[rr][j]);
            }
        }
        __syncthreads();
    }

    float asv[16], adv[16];
#pragma unroll
    for (int j = 0; j < 16; ++j) { asv[j] = attS[head * 16 + j]; adv[j] = attD[head * 16 + j]; }

#pragma unroll
    for (int rr = 0; rr < 4; ++rr) {
        int r = rbase + r0 + rr * 32;
        if (r < n) {
            float ds = 0.f, dd = 0.f;
#pragma unroll
            for (int j = 0; j < 16; ++j) { ds = fmaf(acc[rr][j], asv[j], ds); dd = fmaf(acc[rr][j], adv[j], dd); }
            als[r * 8 + head] = ds;
            ald[r * 8 + head] = dd;
            unsigned short xb[16];
#pragma unroll
            for (int j = 0; j < 16; ++j) {
                __hip_bfloat16 t = __float2bfloat16(acc[rr][j]);
                xb[j] = *reinterpret_cast<unsigned short*>(&t);
            }
            *(uint4*)&xpb[r * 128 + head * 16]     = *(uint4*)&xb[0];
            *(uint4*)&xpb[r * 128 + head * 16 + 8] = *(uint4*)&xb[8];
        }
    }
}

// ---------------- fused wave-per-node softmax + gather (SINGLE PASS) ----------------
// Unnormalized accumulation: y = (sum_e exp(v_e) * x_e) / (sum_e exp(v_e)).
// One edge-list scan: per batch of 8 edges, all 64 lanes compute exp(v) for
// (edge ee, head hd), accumulate per-head partial denominators in registers,
// stash weights in LDS, gather 8 xp rows; denominator reduced once at the end.

__global__ __launch_bounds__(256) void k_agg(
    const unsigned short* __restrict__ xpb, const float* __restrict__ als,
    const float* __restrict__ ald,
    const int* __restrict__ rowptr, const int* __restrict__ colv,
    const float* __restrict__ prevRaw, const float* __restrict__ prevY,
    const float* __restrict__ pst, const float* __restrict__ bias,
    float* __restrict__ y, int n)
{
    __shared__ float alds[4][8][8];   // [wave][edge][head]
    __shared__ int   slds[4][8];      // [wave][edge]
    int wv = threadIdx.x >> 6;
    int wid = (int)((blockIdx.x * blockDim.x + threadIdx.x) >> 6);
    int lane = threadIdx.x & 63;
    if (wid >= n) return;
    int rs = rowptr[wid], re = rowptr[wid + 1];
    int deg = re - rs;

    int hd = lane & 7;
    int ee = lane >> 3;
    float aldn = ald[wid * 8 + hd];
    int q = lane >> 3;
    int c0 = lane * 2;

    float a0 = 0.f, a1 = 0.f, smloc = 0.f;
    int full = deg & ~7;

    for (int b0 = 0; b0 < full; b0 += 8) {
        int se = colv[rs + b0 + ee];
        float v = als[se * 8 + hd] + aldn;
        v = v > 0.f ? v : 0.2f * v;
        float al = expf(v);
        smloc += al;
        alds[wv][ee][hd] = al;
        if (hd == 0) slds[wv][ee] = se;
#pragma unroll
        for (int j = 0; j < 8; ++j) {
            int s = slds[wv][j];
            float a = alds[wv][j][q];
            ushort2 xv = *(const ushort2*)(xpb + (size_t)s * 128 + c0);
            a0 = fmaf(a, bf2f(xv.x), a0);
            a1 = fmaf(a, bf2f(xv.y), a1);
        }
    }

    if (full < deg) {
        int nb = deg - full;
        float al = 0.f;
        int se = 0;
        if (ee < nb) {
            se = colv[rs + full + ee];
            float v = als[se * 8 + hd] + aldn;
            v = v > 0.f ? v : 0.2f * v;
            al = expf(v);
            smloc += al;
        }
        alds[wv][ee][hd] = al;
        if (hd == 0) slds[wv][ee] = se;
        for (int j = 0; j < nb; ++j) {
            int s = slds[wv][j];
            float a = alds[wv][j][q];
            ushort2 xv = *(const ushort2*)(xpb + (size_t)s * 128 + c0);
            a0 = fmaf(a, bf2f(xv.x), a0);
            a1 = fmaf(a, bf2f(xv.y), a1);
        }
    }

    // reduce denominators across edge-slots (same head), then fetch head q's total
    smloc += __shfl_xor(smloc, 8);
    smloc += __shfl_xor(smloc, 16);
    smloc += __shfl_xor(smloc, 32);
    float inv = 1.f / __shfl(smloc, q);   // lane q (q<8) holds head q's denom
    a0 *= inv;
    a1 *= inv;

    float p0 = 0.f, p1 = 0.f;
    if (prevY) {
        float2 yv = *(const float2*)(prevY + (size_t)wid * 128 + c0);
        p0 = eluf(fmaf(yv.x, pst[c0], pst[128 + c0]));
        p1 = eluf(fmaf(yv.y, pst[c0 + 1], pst[129 + c0]));
    } else if (prevRaw) {
        p0 = prevRaw[(size_t)wid * 128 + c0];
        p1 = prevRaw[(size_t)wid * 128 + c0 + 1];
    }
    y[wid * 128 + c0] = p0 + a0 + bias[c0];
    y[wid * 128 + c0 + 1] = p1 + a1 + bias[c0 + 1];
}

// ---------------- layernorm over axis 0 ----------------

__global__ __launch_bounds__(256) void k_stats(const float* __restrict__ y,
                                               double* __restrict__ partial, int n) {
    int col = threadIdx.x & 127;
    int rg = threadIdx.x >> 7;
    double s = 0.0, s2 = 0.0;
    for (int r = blockIdx.x * 2 + rg; r < n; r += SWG * 2) {
        float v = y[r * 128 + col];
        s += v; s2 += (double)v * (double)v;
    }
    __shared__ double ls[256], ls2[256];
    ls[threadIdx.x] = s; ls2[threadIdx.x] = s2;
    __syncthreads();
    if (rg == 0) {
        s += ls[threadIdx.x + 128];
        s2 += ls2[threadIdx.x + 128];
        partial[col * SWG + blockIdx.x] = s;
        partial[128 * SWG + col * SWG + blockIdx.x] = s2;
    }
}

// finishes stats AND bakes gamma/beta into affine scale/shift:
// st[col] = gamma*rsig, st[128+col] = beta - mu*gamma*rsig
__global__ void k_stats_fin(const double* __restrict__ partial,
                            const float* __restrict__ gamma,
                            const float* __restrict__ beta,
                            float* __restrict__ st, int n) {
    int col = threadIdx.x;  // 128 threads
    double s = 0.0, s2 = 0.0;
    for (int w = 0; w < SWG; ++w) {
        s += partial[col * SWG + w];
        s2 += partial[128 * SWG + col * SWG + w];
    }
    double mu = s / n;
    double var = s2 / n - mu * mu;
    double rsig = 1.0 / sqrt(var + 1e-5);
    double sc = (double)gamma[col] * rsig;
    st[col] = (float)sc;
    st[128 + col] = (float)((double)beta[col] - mu * sc);
}

// ---------------- pooling: split stage + reduce/readout ----------------
// stage 1 applies elu(Y*sc+sh) on the fly.

__global__ __launch_bounds__(256) void k_pool_part(
    const float* __restrict__ Y, const float* __restrict__ st,
    const void* __restrict__ batch, const int* __restrict__ flag,
    float* __restrict__ ppart, int n)
{
    int g = blockIdx.x / PSP;
    int sp = blockIdx.x % PSP;
    int is64 = flag[0];
    int lo = 0, hi = n;
    while (lo < hi) { int mid = (lo + hi) >> 1; if (geti(batch, mid, is64) < g) lo = mid + 1; else hi = mid; }
    int start = lo;
    hi = n;
    while (lo < hi) { int mid = (lo + hi) >> 1; if (geti(batch, mid, is64) < g + 1) lo = mid + 1; else hi = mid; }
    int end = lo;
    int cnt = end - start;
    int slice = (cnt + PSP - 1) / PSP;
    int s0 = start + sp * slice;
    int s1 = s0 + slice; if (s1 > end) s1 = end;

    int col = threadIdx.x & 127;
    int half = threadIdx.x >> 7;
    float sc = st[col], sh = st[128 + col];
    float s = 0.f;
    for (int r = s0 + half; r < s1; r += 2)
        s += eluf(fmaf(Y[(size_t)r * 128 + col], sc, sh));
    __shared__ float ls[256];
    ls[threadIdx.x] = s;
    __syncthreads();
    if (half == 0) ppart[(g * PSP + sp) * 128 + col] = s + ls[col + 128];
}

__global__ __launch_bounds__(128) void k_pool_fin(
    const float* __restrict__ ppart, const void* __restrict__ batch,
    const int* __restrict__ flag, const float* __restrict__ row,
    const float* __restrict__ rob, float* __restrict__ out, int n)
{
    int g = blockIdx.x;
    int is64 = flag[0];
    int lo = 0, hi = n;
    while (lo < hi) { int mid = (lo + hi) >> 1; if (geti(batch, mid, is64) < g) lo = mid + 1; else hi = mid; }
    int start = lo;
    hi = n;
    while (lo < hi) { int mid = (lo + hi) >> 1; if (geti(batch, mid, is64) < g + 1) lo = mid + 1; else hi = mid; }
    int cnt = lo - start;

    int col = threadIdx.x;   // 128
    float s = 0.f;
#pragma unroll
    for (int sp = 0; sp < PSP; ++sp) s += ppart[(g * PSP + sp) * 128 + col];
    __shared__ float ls[128];
    ls[col] = s * (1.f / fmaxf((float)cnt, 1.f));
    __syncthreads();
    if (col < 2) {
        float acc = 0.f;
        for (int c = 0; c < 128; ++c) acc = fmaf(ls[c], row[c * 2 + col], acc);
        out[g * 2 + col] = acc + rob[col];
    }
}

// ---------------- launch ----------------

extern "C" void kernel_launch(void* const* d_in, const int* in_sizes, int n_in,
                              void* d_out, int out_size, void* d_ws, size_t ws_size,
                              hipStream_t stream) {
    const float* x     = (const float*)d_in[0];
    const void*  ei    = d_in[1];
    const void*  batch = d_in[2];
    const float* W     = (const float*)d_in[3];
    const float* attS  = (const float*)d_in[4];
    const float* attD  = (const float*)d_in[5];
    const float* bias  = (const float*)d_in[6];
    const float* gamma = (const float*)d_in[7];
    const float* beta  = (const float*)d_in[8];
    const float* row   = (const float*)d_in[9];
    const float* rob   = (const float*)d_in[10];
    float* out = (float*)d_out;

    char* wsb = (char*)d_ws;
    size_t off = 0;
    auto alloc = [&](size_t bytes) {
        void* p = wsb + off;
        off += (bytes + 255) & ~(size_t)255;
        return p;
    };
    int*    flag    = (int*)alloc(256);
    int*    rowptr  = (int*)alloc((size_t)(NN + 1) * 4);
    int*    cnts    = (int*)alloc((size_t)NN * 4 * 2);   // counts + fill
    int*    bsum    = (int*)alloc((size_t)256 * 4);
    int*    colv    = (int*)alloc((size_t)MM * 4);
    double* partial = (double*)alloc((size_t)128 * SWG * 2 * 8);
    float*  st1     = (float*)alloc(256 * 4);
    float*  st2     = (float*)alloc(256 * 4);
    float*  st3     = (float*)alloc(256 * 4);
    float*  ppart   = (float*)alloc((size_t)GG * PSP * 128 * 4);
    float*  ALS     = (float*)alloc((size_t)NN * 8 * 4);
    float*  ALD     = (float*)alloc((size_t)NN * 8 * 4);
    unsigned short* XPB = (unsigned short*)alloc((size_t)NN * 128 * 2);
    float* Y1 = (float*)alloc((size_t)NN * 128 * 4);
    float* Y2 = (float*)alloc((size_t)NN * 128 * 4);
    float* Y3 = (float*)alloc((size_t)NN * 128 * 4);
    (void)ws_size; (void)in_sizes; (void)n_in; (void)out_size;

    int* fill = cnts + NN;
    const int GB = (NN + 127) / 128;   // gemm blocks
    const int GA = (NN + 3) / 4;       // agg blocks

    hipLaunchKernelGGL(k_detect, dim3(1), dim3(64), 0, stream, (const int*)ei, flag);
    hipLaunchKernelGGL(k_zero, dim3((2 * NN + 255) / 256), dim3(256), 0, stream, cnts, 2 * NN);
    hipLaunchKernelGGL(k_count, dim3((MM + 255) / 256), dim3(256), 0, stream, ei, flag, cnts);
    hipLaunchKernelGGL(k_scan1, dim3(NSB), dim3(256), 0, stream, cnts, rowptr, bsum);
    hipLaunchKernelGGL(k_scan2, dim3(1), dim3(256), 0, stream, bsum);
    hipLaunchKernelGGL(k_scan3, dim3(NSB), dim3(256), 0, stream, rowptr, bsum);
    hipLaunchKernelGGL(k_fill, dim3((MM + 255) / 256), dim3(256), 0, stream, ei, flag, rowptr, fill, colv);

    // ---- layer 0: h = x (raw), prev = 0 ----
    hipLaunchKernelGGL(k_gemm_att, dim3(GB), dim3(256), 0, stream,
                       x, (const float*)nullptr, (const float*)nullptr,
                       W, attS, attD, XPB, ALS, ALD, NN);
    hipLaunchKernelGGL(k_agg, dim3(GA), dim3(256), 0, stream,
                       XPB, ALS, ALD, rowptr, colv,
                       (const float*)nullptr, (const float*)nullptr, (const float*)nullptr,
                       bias, Y1, NN);
    hipLaunchKernelGGL(k_stats, dim3(SWG), dim3(256), 0, stream, Y1, partial, NN);
    hipLaunchKernelGGL(k_stats_fin, dim3(1), dim3(128), 0, stream, partial, gamma, beta, st1, NN);

    // ---- layer 1: h = E1(Y1), prev = x (raw) ----
    hipLaunchKernelGGL(k_gemm_att, dim3(GB), dim3(256), 0, stream,
                       (const float*)nullptr, Y1, st1,
                       W + 16384, attS + 128, attD + 128, XPB, ALS, ALD, NN);
    hipLaunchKernelGGL(k_agg, dim3(GA), dim3(256), 0, stream,
                       XPB, ALS, ALD, rowptr, colv,
                       x, (const float*)nullptr, (const float*)nullptr,
                       bias + 128, Y2, NN);
    hipLaunchKernelGGL(k_stats, dim3(SWG), dim3(256), 0, stream, Y2, partial, NN);
    hipLaunchKernelGGL(k_stats_fin, dim3(1), dim3(128), 0, stream, partial, gamma + 128, beta + 128, st2, NN);

    // ---- layer 2: h = E2(Y2), prev = E1(Y1) ----
    hipLaunchKernelGGL(k_gemm_att, dim3(GB), dim3(256), 0, stream,
                       (const float*)nullptr, Y2, st2,
                       W + 32768, attS + 256, attD + 256, XPB, ALS, ALD, NN);
    hipLaunchKernelGGL(k_agg, dim3(GA), dim3(256), 0, stream,
                       XPB, ALS, ALD, rowptr, colv,
                       (const float*)nullptr, Y1, st1,
                       bias + 256, Y3, NN);
    hipLaunchKernelGGL(k_stats, dim3(SWG), dim3(256), 0, stream, Y3, partial, NN);
    hipLaunchKernelGGL(k_stats_fin, dim3(1), dim3(128), 0, stream, partial, gamma + 256, beta + 256, st3, NN);

    // ---- pooling on E3(Y3) ----
    hipLaunchKernelGGL(k_pool_part, dim3(GG * PSP), dim3(256), 0, stream,
                       Y3, st3, batch, flag, ppart, NN);
    hipLaunchKernelGGL(k_pool_fin, dim3(GG), dim3(128), 0, stream,
                       ppart, batch, flag, row, rob, out, NN);
}